// Round 11
// baseline (273.989 us; speedup 1.0000x reference)
//
#include <hip/hip_runtime.h>
#include <math.h>

// ---------------------------------------------------------------------------
// PairwiseFeatureBatch: N=512, B=2, D=128, O=16, H=64, CH=48
//   out0: S [512,512,2,16] f32 ; out1: S_skip [511,2,16] f32
// ws (floats): xc@0 x2c@131328 x3c@262656 Sd@393984 pk@8782592(short area)
//              Ya@8881920 Yb@8947456 Q@9012992 segTot@9078656
// 5 dispatches: setup_fused -> scan_fix -> pre_gemm -> pair_mlp -> conv_mfma
// r11: pair_mlp occupancy push. r10 showed ~25us/block lifetime with ~5k busy
//      cycles (90% stall, latency-bound) — so: LDS 32->16KB (hl folded into
//      hh's upper half, used only by the 16 skip blocks) and
//      __launch_bounds__(256,8) -> target 8 blocks/CU (was 4).
// ---------------------------------------------------------------------------

typedef __attribute__((ext_vector_type(8))) short s8v;
typedef __attribute__((ext_vector_type(4))) float f4v;

union U8 { int i[4]; s8v s; };

__device__ __forceinline__ unsigned short f2bf(float f){
  unsigned u = __float_as_uint(f);
  unsigned r = u + 0x7FFFu + ((u >> 16) & 1u);
  return (unsigned short)(r >> 16);
}
__device__ __forceinline__ float bf2f(unsigned short h){
  return __uint_as_float(((unsigned)h) << 16);
}
// exact-GELU via branch-free erf approx (A&S 7.1.26, |err|<=1.5e-7)
__device__ __forceinline__ float gelu_f(float v){
  const float z  = v * 0.7071067811865476f;
  const float az = __builtin_fabsf(z);
  const float t  = __builtin_amdgcn_rcpf(1.0f + 0.3275911f * az);
  float p = 1.061405429f;
  p = p * t - 1.453152027f;
  p = p * t + 1.421413741f;
  p = p * t - 0.284496736f;
  p = p * t + 0.254829592f;
  p = p * t;
  const float e  = __expf(-az * az);
  const float ea = 1.0f - p * e;
  const float er = __uint_as_float((__float_as_uint(z) & 0x80000000u) | __float_as_uint(ea));
  return 0.5f * v * (1.0f + er);
}
__device__ __forceinline__ int inv_tri(int p){
  float t = sqrtf(8.0f * (float)p + 1.0f);
  int i = (int)((t - 1.0f) * 0.5f);
  while ((i + 1) * (i + 2) / 2 <= p) ++i;
  while (i * (i + 1) / 2 > p) --i;
  return i;
}
// truncation hi/lo split, v_perm packing (hi exact-residual: lo = f - hi)
__device__ __forceinline__ void cvt8(const float v[8], s8v& hi, s8v& lo){
  U8 H, L;
#pragma unroll
  for (int t = 0; t < 4; ++t){
    const unsigned a = __float_as_uint(v[2*t]);
    const unsigned b = __float_as_uint(v[2*t+1]);
    H.i[t] = (int)__builtin_amdgcn_perm(b, a, 0x07060302u);
    const float la = v[2*t]   - __uint_as_float(a & 0xFFFF0000u);
    const float lb = v[2*t+1] - __uint_as_float(b & 0xFFFF0000u);
    L.i[t] = (int)__builtin_amdgcn_perm(__float_as_uint(lb), __float_as_uint(la), 0x07060302u);
  }
  hi = H.s; lo = L.s;
}
// RTN bf16 pack (no residual)
__device__ __forceinline__ void cvt8r(const float v[8], s8v& hi){
  U8 H;
#pragma unroll
  for (int t = 0; t < 4; ++t)
    H.i[t] = ((unsigned)f2bf(v[2*t+1]) << 16) | (unsigned)f2bf(v[2*t]);
  hi = H.s;
}
__device__ __forceinline__ void ld8(const float* p, float v[8]){
  const float4 a0 = *(const float4*)p;
  const float4 a1 = *(const float4*)(p + 4);
  v[0]=a0.x; v[1]=a0.y; v[2]=a0.z; v[3]=a0.w;
  v[4]=a1.x; v[5]=a1.y; v[6]=a1.z; v[7]=a1.w;
}

// packed-area short offsets
#define W1H 0
#define W1L 49152
#define W2H 98304
#define W2L 102400
#define W3H 106496
#define W3L 107520
#define S1H 108544
#define S1L 133120
#define S2H 157696
#define S2L 161792
#define S3H 165888
#define S3L 166912
#define C1H 167936
#define C1L 175616
#define C2H 183296
#define C2L 190976

#define MFMA16 __builtin_amdgcn_mfma_f32_16x16x32_bf16

// ----------------------- fused setup (packs + scan phase 1) ----------------
__device__ __forceinline__ void pw_dev(const float* __restrict__ W,
    int K, int KS, int nEl, short* __restrict__ hiD, short* __restrict__ loD, int pos)
{
  if (pos >= nEl) return;
  const int j = pos & 7, lane = (pos >> 3) & 63, t2 = pos >> 9;
  const int ks = t2 % KS, nt = t2 / KS;
  const int n = nt * 16 + (lane & 15);
  const int k = ks * 32 + ((lane >> 4) & 3) * 8 + j;
  const float v = W[n * K + k];
  const unsigned short h = f2bf(v);
  hiD[pos] = (short)h;
  loD[pos] = (short)f2bf(v - bf2f(h));
}
__device__ __forceinline__ void pc1_dev(const float* __restrict__ W,
    short* __restrict__ hiD, int pos)
{
  if (pos >= 7680) return;
  const int j = pos & 7, lane = (pos >> 3) & 63, t2 = pos >> 9;
  const int ks = t2 % 5, chunk = t2 / 5;
  const int n = chunk * 16 + (lane & 15);
  const int k = ks * 32 + ((lane >> 4) & 3) * 8 + j;
  const int tap = k >> 4, ic = k & 15;
  const float v = (tap < 9) ? W[(n * 16 + ic) * 9 + tap] : 0.0f;
  hiD[pos] = (short)f2bf(v);
}
__device__ __forceinline__ void pc2_dev(const float* __restrict__ W,
    short* __restrict__ hiD, int pos)
{
  if (pos >= 7680) return;
  const int j = pos & 7, lane = (pos >> 3) & 63, t2 = pos >> 9;
  const int ks = t2 % 5, chunk = t2 / 5;
  const int n = lane & 15;
  const int k = ks * 32 + ((lane >> 4) & 3) * 8 + j;
  const int tap = k >> 4, ic = chunk * 16 + (k & 15);
  const float v = (tap < 9) ? W[(n * 48 + ic) * 9 + tap] : 0.0f;
  hiD[pos] = (short)f2bf(v);
}

__global__ __launch_bounds__(256) void setup_fused(
    const float* __restrict__ x,
    const float* __restrict__ w1, const float* __restrict__ w2,
    const float* __restrict__ w3, const float* __restrict__ sw1,
    const float* __restrict__ sw2, const float* __restrict__ sw3,
    const float* __restrict__ cw1, const float* __restrict__ cw2,
    float* __restrict__ xc, float* __restrict__ x2c, float* __restrict__ x3c,
    short* __restrict__ pk, float* __restrict__ segTot)
{
  const int b = blockIdx.x, tid = threadIdx.x;
  if (b < 192)      pw_dev(w1, 768, 24, 49152, pk + W1H, pk + W1L, b * 256 + tid);
  else if (b < 208) pw_dev(w2,  64,  2,  4096, pk + W2H, pk + W2L, (b-192) * 256 + tid);
  else if (b < 212) pw_dev(w3,  64,  2,  1024, pk + W3H, pk + W3L, (b-208) * 256 + tid);
  else if (b < 308) pw_dev(sw1,384, 12, 24576, pk + S1H, pk + S1L, (b-212) * 256 + tid);
  else if (b < 324) pw_dev(sw2, 64,  2,  4096, pk + S2H, pk + S2L, (b-308) * 256 + tid);
  else if (b < 328) pw_dev(sw3, 64,  2,  1024, pk + S3H, pk + S3L, (b-324) * 256 + tid);
  else if (b < 358) pc1_dev(cw1, pk + C1H, (b-328) * 256 + tid);
  else if (b < 388) pc2_dev(cw2, pk + C2H, (b-358) * 256 + tid);
  else {
    // scan phase 1: 96 blocks = 3 moments x 32 segments of 16 rows.
    const int t = b - 388;
    const int mom = t >> 5, seg = t & 31;
    float* dst = (mom == 0) ? xc : ((mom == 1) ? x2c : x3c);
    const int col = tid;
    if (seg == 0) dst[col] = 0.0f;
    float v[16];
    const int n0 = seg * 16;
#pragma unroll
    for (int k = 0; k < 16; ++k){
      float u = x[(n0 + k) * 256 + col];
      if (mom == 1) u = u * u;
      else if (mom == 2) u = u * u * u;
      v[k] = u;
    }
    float acc = 0.0f;
#pragma unroll
    for (int k = 0; k < 16; ++k){
      acc += v[k];
      dst[(n0 + k + 1) * 256 + col] = acc;
    }
    segTot[t * 256 + col] = acc;
  }
}

// scan phase 2: add exclusive segment offsets.
__global__ __launch_bounds__(256) void scan_fix(
    float* __restrict__ xc, float* __restrict__ x2c, float* __restrict__ x3c,
    const float* __restrict__ segTot)
{
  const int t = blockIdx.x;              // 0..95
  const int mom = t >> 5, seg = t & 31;
  if (seg == 0) return;
  const int col = threadIdx.x;
  float* dst = (mom == 0) ? xc : ((mom == 1) ? x2c : x3c);
  float off = 0.0f;
  for (int s = 0; s < seg; ++s) off += segTot[(mom * 32 + s) * 256 + col];
  const int n0 = seg * 16;
#pragma unroll
  for (int k = 0; k < 16; ++k)
    dst[(n0 + k + 1) * 256 + col] += off;
}

// -------------------- precompute Ya, Yb, Q (tiny GEMMs) --------------------
__global__ __launch_bounds__(256) void pre_gemm(
    const float* __restrict__ x, const float* __restrict__ xc,
    const float* __restrict__ x2c, const float* __restrict__ x3c,
    const short* __restrict__ pk,
    float* __restrict__ Ya, float* __restrict__ Yb, float* __restrict__ Q)
{
  const int tid = threadIdx.x, wave = tid >> 6, lane = tid & 63;
  const int m = lane & 15, quad = lane >> 4;
  if (blockIdx.x < 16){
    const int row0 = blockIdx.x * 64 + wave * 16;
    f4v accA[4], accB[4];
#pragma unroll
    for (int nt = 0; nt < 4; ++nt){
      accA[nt] = (f4v){0.f,0.f,0.f,0.f};
      accB[nt] = (f4v){0.f,0.f,0.f,0.f};
    }
    for (int ks = 0; ks < 4; ++ks){
      const int d0 = ks * 32 + quad * 8;
      s8v ah, al;
      float v[8];
      ld8(x + (row0 + m) * 128 + d0, v);
      cvt8(v, ah, al);
#pragma unroll
      for (int nt = 0; nt < 4; ++nt){
        const int foA = ((nt * 24 + ks) * 64 + lane) << 3;
        const int foB = ((nt * 24 + 4 + ks) * 64 + lane) << 3;
        const s8v bhA = *(const s8v*)(pk + W1H + foA);
        const s8v blA = *(const s8v*)(pk + W1L + foA);
        const s8v bhB = *(const s8v*)(pk + W1H + foB);
        const s8v blB = *(const s8v*)(pk + W1L + foB);
        accA[nt] = MFMA16(ah, bhA, accA[nt], 0, 0, 0);
        accA[nt] = MFMA16(al, bhA, accA[nt], 0, 0, 0);
        accA[nt] = MFMA16(ah, blA, accA[nt], 0, 0, 0);
        accB[nt] = MFMA16(ah, bhB, accB[nt], 0, 0, 0);
        accB[nt] = MFMA16(al, bhB, accB[nt], 0, 0, 0);
        accB[nt] = MFMA16(ah, blB, accB[nt], 0, 0, 0);
      }
    }
#pragma unroll
    for (int nt = 0; nt < 4; ++nt)
#pragma unroll
      for (int reg = 0; reg < 4; ++reg){
        const int r2 = row0 + quad * 4 + reg;
        const int col = nt * 16 + m;
        Ya[r2 * 64 + col] = accA[nt][reg];
        Yb[r2 * 64 + col] = accB[nt][reg];
      }
  } else {
    const int row0 = (blockIdx.x - 16) * 64 + wave * 16;
    f4v acc[4];
#pragma unroll
    for (int nt = 0; nt < 4; ++nt) acc[nt] = (f4v){0.f,0.f,0.f,0.f};
    int rr = row0 + m; if (rr > 1025) rr = 1025;
#pragma unroll
    for (int c = 0; c < 3; ++c){
      const float* src = (c == 0) ? xc : ((c == 1) ? x2c : x3c);
      for (int ks = 0; ks < 4; ++ks){
        const int d0 = ks * 32 + quad * 8;
        s8v ah, al;
        float v[8];
        ld8(src + rr * 128 + d0, v);
        cvt8(v, ah, al);
#pragma unroll
        for (int nt = 0; nt < 4; ++nt){
          const int fo = ((nt * 24 + (c + 3) * 4 + ks) * 64 + lane) << 3;
          const s8v bh = *(const s8v*)(pk + W1H + fo);
          const s8v bl = *(const s8v*)(pk + W1L + fo);
          acc[nt] = MFMA16(ah, bh, acc[nt], 0, 0, 0);
          acc[nt] = MFMA16(al, bh, acc[nt], 0, 0, 0);
          acc[nt] = MFMA16(ah, bl, acc[nt], 0, 0, 0);
        }
      }
    }
#pragma unroll
    for (int nt = 0; nt < 4; ++nt)
#pragma unroll
      for (int reg = 0; reg < 4; ++reg){
        const int r2 = row0 + quad * 4 + reg;
        if (r2 < 1026) Q[r2 * 64 + nt * 16 + m] = acc[nt][reg];
      }
  }
}

// ---------------- pairwise MLP (blocks 0..2051) + skip (2052..2067) --------
// pair: pure bf16-RTN, hh-only (16KB LDS). skip: hi in hh[w][0..1023],
// lo in hh[w][1024..2047] (its footprint is 1024 shorts/wave).
// launch_bounds(256,8): 8 blocks/CU target (r10 was 4 -> Occ 33%, 90% stall).
__global__ __launch_bounds__(256, 8) void pair_mlp(
    const float* __restrict__ x, const short* __restrict__ pk,
    const float* __restrict__ Ya, const float* __restrict__ Yb,
    const float* __restrict__ Q,
    const float* __restrict__ b1, const float* __restrict__ b2,
    const float* __restrict__ b3,
    const float* __restrict__ sb1, const float* __restrict__ sb2,
    const float* __restrict__ sb3,
    float* __restrict__ Sd, float* __restrict__ outK)
{
  __shared__ __attribute__((aligned(16))) short hh[4][2048];
  const int tid = threadIdx.x;
  const int wave = tid >> 6, lane = tid & 63;
  const int m = lane & 15, quad = lane >> 4;

  if (blockIdx.x >= 2052){
    // ------------------------- skip MLP path (hi/lo) -----------------------
    const int rowBase = (blockIdx.x - 2052) * 64 + wave * 16;
    int r = rowBase + m; if (r > 1021) r = 1021;
    const int nidx = r >> 1, bb = r & 1;
    const int oi = (nidx * 2 + bb) * 128, oj = ((nidx + 1) * 2 + bb) * 128;

    f4v acc[4];
#pragma unroll
    for (int nt = 0; nt < 4; ++nt) acc[nt] = (f4v){0.f,0.f,0.f,0.f};

    for (int d4 = 0; d4 < 4; ++d4){
      const int d0 = d4 * 32 + quad * 8;
      float vi[8], vj[8];
      ld8(x + oi + d0, vi); ld8(x + oj + d0, vj);
#pragma unroll
      for (int cc = 0; cc < 3; ++cc){
        const int c = (cc == 0) ? 2 : (cc - 1);
        s8v ah, al;
        if (c == 2){
          float vp[8];
#pragma unroll
          for (int t = 0; t < 8; ++t) vp[t] = vi[t] * vj[t];
          cvt8(vp, ah, al);
        } else if (c == 0) cvt8(vi, ah, al);
        else               cvt8(vj, ah, al);
        const int ks = c * 4 + d4;
#pragma unroll
        for (int nt = 0; nt < 4; ++nt){
          const int fo = ((nt * 12 + ks) * 64 + lane) << 3;
          const s8v bh = *(const s8v*)(pk + S1H + fo);
          const s8v bl = *(const s8v*)(pk + S1L + fo);
          acc[nt] = MFMA16(ah, bh, acc[nt], 0, 0, 0);
          acc[nt] = MFMA16(al, bh, acc[nt], 0, 0, 0);
          acc[nt] = MFMA16(ah, bl, acc[nt], 0, 0, 0);
        }
      }
    }
#pragma unroll
    for (int nt = 0; nt < 4; ++nt){
      const float bias = sb1[nt * 16 + m];
#pragma unroll
      for (int reg = 0; reg < 4; ++reg){
        const float v = gelu_f(acc[nt][reg] + bias);
        const int idx = (quad * 4 + reg) * 64 + ((nt * 16 + m) ^ (quad << 4));
        const unsigned uv = __float_as_uint(v);
        hh[wave][idx] = (short)(uv >> 16);
        const float lo = v - __uint_as_float(uv & 0xFFFF0000u);
        hh[wave][1024 + idx] = (short)(__float_as_uint(lo) >> 16);
      }
    }
    s8v a2h[2], a2l[2];
#pragma unroll
    for (int k2 = 0; k2 < 2; ++k2){
      const int off = m * 64 + ((k2 * 32 + quad * 8) ^ ((m >> 2) << 4));
      a2h[k2] = *(const s8v*)&hh[wave][off];
      a2l[k2] = *(const s8v*)&hh[wave][1024 + off];
    }
    f4v acc2[4];
#pragma unroll
    for (int nt = 0; nt < 4; ++nt) acc2[nt] = (f4v){0.f,0.f,0.f,0.f};
#pragma unroll
    for (int k2 = 0; k2 < 2; ++k2)
#pragma unroll
      for (int nt = 0; nt < 4; ++nt){
        const int fo = ((nt * 2 + k2) * 64 + lane) << 3;
        const s8v bh = *(const s8v*)(pk + S2H + fo);
        const s8v bl = *(const s8v*)(pk + S2L + fo);
        acc2[nt] = MFMA16(a2h[k2], bh, acc2[nt], 0, 0, 0);
        acc2[nt] = MFMA16(a2l[k2], bh, acc2[nt], 0, 0, 0);
        acc2[nt] = MFMA16(a2h[k2], bl, acc2[nt], 0, 0, 0);
      }
#pragma unroll
    for (int nt = 0; nt < 4; ++nt){
      const float bias = sb2[nt * 16 + m];
#pragma unroll
      for (int reg = 0; reg < 4; ++reg){
        const float v = gelu_f(acc2[nt][reg] + bias);
        const int idx = (quad * 4 + reg) * 64 + ((nt * 16 + m) ^ (quad << 4));
        const unsigned uv = __float_as_uint(v);
        hh[wave][idx] = (short)(uv >> 16);
        const float lo = v - __uint_as_float(uv & 0xFFFF0000u);
        hh[wave][1024 + idx] = (short)(__float_as_uint(lo) >> 16);
      }
    }
    s8v a3h[2], a3l[2];
#pragma unroll
    for (int k3 = 0; k3 < 2; ++k3){
      const int off = m * 64 + ((k3 * 32 + quad * 8) ^ ((m >> 2) << 4));
      a3h[k3] = *(const s8v*)&hh[wave][off];
      a3l[k3] = *(const s8v*)&hh[wave][1024 + off];
    }
    f4v acc3 = (f4v){0.f,0.f,0.f,0.f};
#pragma unroll
    for (int k3 = 0; k3 < 2; ++k3){
      const int fo = (k3 * 64 + lane) << 3;
      const s8v bh = *(const s8v*)(pk + S3H + fo);
      const s8v bl = *(const s8v*)(pk + S3L + fo);
      acc3 = MFMA16(a3h[k3], bh, acc3, 0, 0, 0);
      acc3 = MFMA16(a3l[k3], bh, acc3, 0, 0, 0);
      acc3 = MFMA16(a3h[k3], bl, acc3, 0, 0, 0);
    }
    const float bias3 = sb3[m];
#pragma unroll
    for (int reg = 0; reg < 4; ++reg){
      const int R = rowBase + quad * 4 + reg;
      if (R < 1022) outK[R * 16 + m] = acc3[reg] + bias3;
    }
    return;
  }

  // --------------------------- pair path (pure bf16) -----------------------
  const int rowBase = blockIdx.x * 128 + wave * 32;
  int oi[2], oj[2];
  int qa2[2][2], qb2[2][2];
  float invLr[2][2];
#pragma unroll
  for (int s = 0; s < 2; ++s){
    {
      const int r = rowBase + s * 16 + m;
      const int p = r >> 1, b = r & 1;
      const int i = inv_tri(p), j = p - i * (i + 1) / 2;
      oi[s] = (i * 2 + b) * 128;
      oj[s] = (j * 2 + b) * 128;
    }
    {
      const int p0 = (rowBase + s * 16 + quad * 4) >> 1;
      const int i0 = inv_tri(p0), j0 = p0 - i0 * (i0 + 1) / 2;
      qa2[s][0] = (i0 + 1) * 128; qb2[s][0] = j0 * 128;
      invLr[s][0] = 1.0f / (float)(i0 - j0 + 1);
      int i1 = i0, j1 = j0 + 1;
      if (j1 > i1){ i1 = i0 + 1; j1 = 0; }
      qa2[s][1] = (i1 + 1) * 128; qb2[s][1] = j1 * 128;
      invLr[s][1] = 1.0f / (float)(i1 - j1 + 1);
    }
  }

  f4v acc[2][4];
#pragma unroll
  for (int s = 0; s < 2; ++s)
#pragma unroll
    for (int nt = 0; nt < 4; ++nt) acc[s][nt] = (f4v){0.f,0.f,0.f,0.f};

  // layer-1 Hadamard GEMM, K=128, bf16-RTN single MFMA
  for (int d4 = 0; d4 < 4; ++d4){
    const int d0 = d4 * 32 + quad * 8;
    s8v ah[2];
#pragma unroll
    for (int s = 0; s < 2; ++s){
      float vi[8], vj[8];
      ld8(x + oi[s] + d0, vi); ld8(x + oj[s] + d0, vj);
#pragma unroll
      for (int t = 0; t < 8; ++t) vi[t] *= vj[t];
      cvt8r(vi, ah[s]);
    }
#pragma unroll
    for (int nt = 0; nt < 4; ++nt){
      const int fo = ((nt * 24 + 8 + d4) * 64 + lane) << 3;
      const s8v bh = *(const s8v*)(pk + W1H + fo);
#pragma unroll
      for (int s = 0; s < 2; ++s)
        acc[s][nt] = MFMA16(ah[s], bh, acc[s][nt], 0, 0, 0);
    }
  }
  // epilogue 1: + Ya[i] + Yb[j] + invL*(Q[i+1]-Q[j]) + b1, gelu -> LDS (RTN)
#pragma unroll
  for (int s = 0; s < 2; ++s)
#pragma unroll
    for (int nt = 0; nt < 4; ++nt){
      const int col = nt * 16 + m;
      const float bias = b1[col];
#pragma unroll
      for (int reg = 0; reg < 4; ++reg){
        const int k = reg >> 1, bb = reg & 1;
        const int off = bb * 64 + col;
        const float add = Ya[qa2[s][k] - 128 + off] + Yb[qb2[s][k] + off]
                        + invLr[s][k] * (Q[qa2[s][k] + off] - Q[qb2[s][k] + off]);
        const float v = gelu_f(acc[s][nt][reg] + bias + add);
        const int idx = (s * 16 + quad * 4 + reg) * 64 + ((nt * 16 + m) ^ (quad << 4));
        hh[wave][idx] = (short)f2bf(v);
      }
    }
  s8v a2h[2][2];
#pragma unroll
  for (int s = 0; s < 2; ++s)
#pragma unroll
    for (int k2 = 0; k2 < 2; ++k2){
      const int off = (s * 16 + m) * 64 + ((k2 * 32 + quad * 8) ^ ((m >> 2) << 4));
      a2h[s][k2] = *(const s8v*)&hh[wave][off];
    }
  // layer 2 (bf16)
  f4v acc2[2][4];
#pragma unroll
  for (int s = 0; s < 2; ++s)
#pragma unroll
    for (int nt = 0; nt < 4; ++nt) acc2[s][nt] = (f4v){0.f,0.f,0.f,0.f};
#pragma unroll
  for (int k2 = 0; k2 < 2; ++k2)
#pragma unroll
    for (int nt = 0; nt < 4; ++nt){
      const int fo = ((nt * 2 + k2) * 64 + lane) << 3;
      const s8v bh = *(const s8v*)(pk + W2H + fo);
#pragma unroll
      for (int s = 0; s < 2; ++s)
        acc2[s][nt] = MFMA16(a2h[s][k2], bh, acc2[s][nt], 0, 0, 0);
    }
#pragma unroll
  for (int s = 0; s < 2; ++s)
#pragma unroll
    for (int nt = 0; nt < 4; ++nt){
      const float bias = b2[nt * 16 + m];
#pragma unroll
      for (int reg = 0; reg < 4; ++reg){
        const float v = gelu_f(acc2[s][nt][reg] + bias);
        const int idx = (s * 16 + quad * 4 + reg) * 64 + ((nt * 16 + m) ^ (quad << 4));
        hh[wave][idx] = (short)f2bf(v);
      }
    }
  s8v a3h[2][2];
#pragma unroll
  for (int s = 0; s < 2; ++s)
#pragma unroll
    for (int k3 = 0; k3 < 2; ++k3){
      const int off = (s * 16 + m) * 64 + ((k3 * 32 + quad * 8) ^ ((m >> 2) << 4));
      a3h[s][k3] = *(const s8v*)&hh[wave][off];
    }
  // layer 3 (bf16)
  f4v acc3[2];
  acc3[0] = (f4v){0.f,0.f,0.f,0.f};
  acc3[1] = (f4v){0.f,0.f,0.f,0.f};
#pragma unroll
  for (int k3 = 0; k3 < 2; ++k3){
    const int fo = (k3 * 64 + lane) << 3;
    const s8v bh = *(const s8v*)(pk + W3H + fo);
#pragma unroll
    for (int s = 0; s < 2; ++s)
      acc3[s] = MFMA16(a3h[s][k3], bh, acc3[s], 0, 0, 0);
  }
  const float bias3 = b3[m];
#pragma unroll
  for (int s = 0; s < 2; ++s)
#pragma unroll
    for (int reg = 0; reg < 4; ++reg){
      const int k = reg >> 1, bb = reg & 1;
      const int i = (qa2[s][k] >> 7) - 1, j = qb2[s][k] >> 7;
      Sd[((i * 512 + j) * 2 + bb) * 16 + m] = acc3[s][reg] + bias3;
    }
}

// ------------- MFMA fused conv1(pad2)+gelu+conv2+len-scale -----------------
// pure bf16-RTN; sT 400x24, hT 324x24 shorts -> 34.8KB LDS, 4 blocks/CU.
__global__ __launch_bounds__(256) void conv_mfma(
    const float* __restrict__ Sd, const short* __restrict__ pk,
    const float* __restrict__ cb1, const float* __restrict__ cb2,
    float* __restrict__ out)
{
  __shared__ __attribute__((aligned(16))) short sT[9600];   // 400 px * 24
  __shared__ __attribute__((aligned(16))) short hT[7776];   // 324 px * 24

  const int tid = threadIdx.x;
  const int X0 = blockIdx.x * 16, Y0 = blockIdx.y * 16, bb = blockIdx.z;
  const int lane = tid & 63, wave = tid >> 6;
  const int mcol = lane & 15, quad = lane >> 4;
  const int tq = quad >> 1, icl0 = (quad & 1) * 8;

  for (int e = tid; e < 1600; e += 256){
    const int q = e & 3, p = e >> 2;
    const int row = p / 20, col = p % 20;
    const int gy = Y0 - 2 + row, gx = X0 - 2 + col;
    float4 v = make_float4(0.f, 0.f, 0.f, 0.f);
    if (gy >= 0 && gy < 512 && gx >= 0 && gx <= gy)
      v = *(const float4*)(Sd + (((gy * 512 + gx) * 2 + bb) * 16 + q * 4));
    int2 pkd;
    pkd.x = ((unsigned)f2bf(v.y) << 16) | (unsigned)f2bf(v.x);
    pkd.y = ((unsigned)f2bf(v.w) << 16) | (unsigned)f2bf(v.z);
    *(int2*)&sT[p * 24 + q * 4] = pkd;
  }
  __syncthreads();

  int base1[6];
#pragma unroll
  for (int it = 0; it < 6; ++it){
    int p = (wave * 6 + it) * 16 + mcol; if (p > 323) p = 323;
    const int u = p / 18, v = p - u * 18;
    base1[it] = (u * 20 + v) * 24 + icl0;
  }
  int base2[4];
#pragma unroll
  for (int t2 = 0; t2 < 4; ++t2){
    const int p = (wave * 4 + t2) * 16 + mcol;
    base2[t2] = (p >> 4) * 18 + (p & 15);
  }

  const float bias2 = cb2[mcol];
  f4v acc2[4];
#pragma unroll
  for (int t2 = 0; t2 < 4; ++t2) acc2[t2] = (f4v){0.f,0.f,0.f,0.f};

  for (int chunk = 0; chunk < 3; ++chunk){
    f4v c1[6];
#pragma unroll
    for (int it = 0; it < 6; ++it) c1[it] = (f4v){0.f,0.f,0.f,0.f};
    for (int ks = 0; ks < 5; ++ks){
      int tap = ks * 2 + tq; if (tap > 8) tap = 8;   // tap9 -> B is zero
      const int ky = tap / 3, kx = tap - ky * 3;
      const int off1 = (ky * 20 + kx) * 24;
      const int fo = ((chunk * 5 + ks) * 64 + lane) << 3;
      const s8v b1h = *(const s8v*)(pk + C1H + fo);
#pragma unroll
      for (int it = 0; it < 6; ++it){
        const s8v ah = *(const s8v*)&sT[base1[it] + off1];
        c1[it] = MFMA16(ah, b1h, c1[it], 0, 0, 0);
      }
    }
    const float bias1 = cb1[chunk * 16 + mcol];
#pragma unroll
    for (int it = 0; it < 6; ++it){
      const int pb = (wave * 6 + it) * 16 + quad * 4;
#pragma unroll
      for (int reg = 0; reg < 4; ++reg){
        const int p = pb + reg;
        if (p < 324)
          hT[p * 24 + mcol] = (short)f2bf(gelu_f(c1[it][reg] + bias1));
      }
    }
    __syncthreads();
    for (int ks = 0; ks < 5; ++ks){
      int tap = ks * 2 + tq; if (tap > 8) tap = 8;
      const int ky = tap / 3, kx = tap - ky * 3;
      const int off2 = ky * 18 + kx;
      const int fo = ((chunk * 5 + ks) * 64 + lane) << 3;
      const s8v b2h = *(const s8v*)(pk + C2H + fo);
#pragma unroll
      for (int t2 = 0; t2 < 4; ++t2){
        const s8v ah = *(const s8v*)&hT[(base2[t2] + off2) * 24 + icl0];
        acc2[t2] = MFMA16(ah, b2h, acc2[t2], 0, 0, 0);
      }
    }
    __syncthreads();
  }
#pragma unroll
  for (int t2 = 0; t2 < 4; ++t2){
#pragma unroll
    for (int reg = 0; reg < 4; ++reg){
      const int p = (wave * 4 + t2) * 16 + quad * 4 + reg;
      const int Y = Y0 + (p >> 4), X = X0 + (p & 15);
      int l = Y - X; if (l < 0) l = -l; if (l < 1) l = 1;
      out[((Y * 512 + X) * 2 + bb) * 16 + mcol] = (acc2[t2][reg] + bias2) * (float)l;
    }
  }
}

// ---------------------------------------------------------------------------
extern "C" void kernel_launch(void* const* d_in, const int* in_sizes, int n_in,
                              void* d_out, int out_size, void* d_ws, size_t ws_size,
                              hipStream_t stream)
{
  (void)in_sizes; (void)n_in; (void)out_size; (void)ws_size;
  const float* x   = (const float*)d_in[0];
  const float* w1  = (const float*)d_in[1];
  const float* b1  = (const float*)d_in[2];
  const float* w2  = (const float*)d_in[3];
  const float* b2  = (const float*)d_in[4];
  const float* w3  = (const float*)d_in[5];
  const float* b3  = (const float*)d_in[6];
  const float* sw1 = (const float*)d_in[7];
  const float* sb1 = (const float*)d_in[8];
  const float* sw2 = (const float*)d_in[9];
  const float* sb2 = (const float*)d_in[10];
  const float* sw3 = (const float*)d_in[11];
  const float* sb3 = (const float*)d_in[12];
  const float* cw1 = (const float*)d_in[13];
  const float* cb1 = (const float*)d_in[14];
  const float* cw2 = (const float*)d_in[15];
  const float* cb2 = (const float*)d_in[16];

  float* ws  = (float*)d_ws;
  float* xc  = ws;
  float* x2c = ws + 131328;
  float* x3c = ws + 262656;
  float* Sd  = ws + 393984;
  short* pk  = (short*)(ws + 8782592);
  float* Ya  = ws + 8881920;
  float* Yb  = ws + 8947456;
  float* Q   = ws + 9012992;
  float* segTot = ws + 9078656;
  float* outS = (float*)d_out;
  float* outK = outS + 8388608;

  setup_fused<<<484, 256, 0, stream>>>(x, w1, w2, w3, sw1, sw2, sw3, cw1, cw2,
                                       xc, x2c, x3c, pk, segTot);
  scan_fix<<<96, 256, 0, stream>>>(xc, x2c, x3c, segTot);
  pre_gemm<<<33, 256, 0, stream>>>(x, xc, x2c, x3c, pk, Ya, Yb, Q);
  pair_mlp<<<2068, 256, 0, stream>>>(x, pk, Ya, Yb, Q, b1, b2, b3,
                                     sb1, sb2, sb3, Sd, outK);
  conv_mfma<<<dim3(32, 32, 2), 256, 0, stream>>>(Sd, pk, cb1, cb2, outS);
}

// Round 12
// 242.628 us; speedup vs baseline: 1.1293x; 1.1293x over previous
//
#include <hip/hip_runtime.h>
#include <math.h>

// ---------------------------------------------------------------------------
// PairwiseFeatureBatch: N=512, B=2, D=128, O=16, H=64, CH=48
//   out0: S [512,512,2,16] f32 ; out1: S_skip [511,2,16] f32
// ws (floats): xc@0 x2c@131328 x3c@262656 Sd@393984 pk@8782592(short area)
//              Ya@8881920 Yb@8947456 Q@9012992 segTot@9078656
// 5 dispatches: setup_fused -> scan_fix -> pre_gemm -> pair_mlp -> conv_mfma
// r12: launch_bounds(256,8)->(256,6). r11's 8-wave cap forced VGPR 64->32 ->
//      scratch spills (WRITE_SIZE 80->150MB, dur 75->102us). At 6 waves/SIMD
//      the cap is ~85 VGPR > the 64-reg natural live set: no spills,
//      6 blocks/CU (75% occ target). LDS stays 16KB (r11's real win).
// ---------------------------------------------------------------------------

typedef __attribute__((ext_vector_type(8))) short s8v;
typedef __attribute__((ext_vector_type(4))) float f4v;

union U8 { int i[4]; s8v s; };

__device__ __forceinline__ unsigned short f2bf(float f){
  unsigned u = __float_as_uint(f);
  unsigned r = u + 0x7FFFu + ((u >> 16) & 1u);
  return (unsigned short)(r >> 16);
}
__device__ __forceinline__ float bf2f(unsigned short h){
  return __uint_as_float(((unsigned)h) << 16);
}
// exact-GELU via branch-free erf approx (A&S 7.1.26, |err|<=1.5e-7)
__device__ __forceinline__ float gelu_f(float v){
  const float z  = v * 0.7071067811865476f;
  const float az = __builtin_fabsf(z);
  const float t  = __builtin_amdgcn_rcpf(1.0f + 0.3275911f * az);
  float p = 1.061405429f;
  p = p * t - 1.453152027f;
  p = p * t + 1.421413741f;
  p = p * t - 0.284496736f;
  p = p * t + 0.254829592f;
  p = p * t;
  const float e  = __expf(-az * az);
  const float ea = 1.0f - p * e;
  const float er = __uint_as_float((__float_as_uint(z) & 0x80000000u) | __float_as_uint(ea));
  return 0.5f * v * (1.0f + er);
}
__device__ __forceinline__ int inv_tri(int p){
  float t = sqrtf(8.0f * (float)p + 1.0f);
  int i = (int)((t - 1.0f) * 0.5f);
  while ((i + 1) * (i + 2) / 2 <= p) ++i;
  while (i * (i + 1) / 2 > p) --i;
  return i;
}
// truncation hi/lo split, v_perm packing (hi exact-residual: lo = f - hi)
__device__ __forceinline__ void cvt8(const float v[8], s8v& hi, s8v& lo){
  U8 H, L;
#pragma unroll
  for (int t = 0; t < 4; ++t){
    const unsigned a = __float_as_uint(v[2*t]);
    const unsigned b = __float_as_uint(v[2*t+1]);
    H.i[t] = (int)__builtin_amdgcn_perm(b, a, 0x07060302u);
    const float la = v[2*t]   - __uint_as_float(a & 0xFFFF0000u);
    const float lb = v[2*t+1] - __uint_as_float(b & 0xFFFF0000u);
    L.i[t] = (int)__builtin_amdgcn_perm(__float_as_uint(lb), __float_as_uint(la), 0x07060302u);
  }
  hi = H.s; lo = L.s;
}
// RTN bf16 pack (no residual)
__device__ __forceinline__ void cvt8r(const float v[8], s8v& hi){
  U8 H;
#pragma unroll
  for (int t = 0; t < 4; ++t)
    H.i[t] = ((unsigned)f2bf(v[2*t+1]) << 16) | (unsigned)f2bf(v[2*t]);
  hi = H.s;
}
__device__ __forceinline__ void ld8(const float* p, float v[8]){
  const float4 a0 = *(const float4*)p;
  const float4 a1 = *(const float4*)(p + 4);
  v[0]=a0.x; v[1]=a0.y; v[2]=a0.z; v[3]=a0.w;
  v[4]=a1.x; v[5]=a1.y; v[6]=a1.z; v[7]=a1.w;
}

// packed-area short offsets
#define W1H 0
#define W1L 49152
#define W2H 98304
#define W2L 102400
#define W3H 106496
#define W3L 107520
#define S1H 108544
#define S1L 133120
#define S2H 157696
#define S2L 161792
#define S3H 165888
#define S3L 166912
#define C1H 167936
#define C1L 175616
#define C2H 183296
#define C2L 190976

#define MFMA16 __builtin_amdgcn_mfma_f32_16x16x32_bf16

// ----------------------- fused setup (packs + scan phase 1) ----------------
__device__ __forceinline__ void pw_dev(const float* __restrict__ W,
    int K, int KS, int nEl, short* __restrict__ hiD, short* __restrict__ loD, int pos)
{
  if (pos >= nEl) return;
  const int j = pos & 7, lane = (pos >> 3) & 63, t2 = pos >> 9;
  const int ks = t2 % KS, nt = t2 / KS;
  const int n = nt * 16 + (lane & 15);
  const int k = ks * 32 + ((lane >> 4) & 3) * 8 + j;
  const float v = W[n * K + k];
  const unsigned short h = f2bf(v);
  hiD[pos] = (short)h;
  loD[pos] = (short)f2bf(v - bf2f(h));
}
__device__ __forceinline__ void pc1_dev(const float* __restrict__ W,
    short* __restrict__ hiD, int pos)
{
  if (pos >= 7680) return;
  const int j = pos & 7, lane = (pos >> 3) & 63, t2 = pos >> 9;
  const int ks = t2 % 5, chunk = t2 / 5;
  const int n = chunk * 16 + (lane & 15);
  const int k = ks * 32 + ((lane >> 4) & 3) * 8 + j;
  const int tap = k >> 4, ic = k & 15;
  const float v = (tap < 9) ? W[(n * 16 + ic) * 9 + tap] : 0.0f;
  hiD[pos] = (short)f2bf(v);
}
__device__ __forceinline__ void pc2_dev(const float* __restrict__ W,
    short* __restrict__ hiD, int pos)
{
  if (pos >= 7680) return;
  const int j = pos & 7, lane = (pos >> 3) & 63, t2 = pos >> 9;
  const int ks = t2 % 5, chunk = t2 / 5;
  const int n = lane & 15;
  const int k = ks * 32 + ((lane >> 4) & 3) * 8 + j;
  const int tap = k >> 4, ic = chunk * 16 + (k & 15);
  const float v = (tap < 9) ? W[(n * 48 + ic) * 9 + tap] : 0.0f;
  hiD[pos] = (short)f2bf(v);
}

__global__ __launch_bounds__(256) void setup_fused(
    const float* __restrict__ x,
    const float* __restrict__ w1, const float* __restrict__ w2,
    const float* __restrict__ w3, const float* __restrict__ sw1,
    const float* __restrict__ sw2, const float* __restrict__ sw3,
    const float* __restrict__ cw1, const float* __restrict__ cw2,
    float* __restrict__ xc, float* __restrict__ x2c, float* __restrict__ x3c,
    short* __restrict__ pk, float* __restrict__ segTot)
{
  const int b = blockIdx.x, tid = threadIdx.x;
  if (b < 192)      pw_dev(w1, 768, 24, 49152, pk + W1H, pk + W1L, b * 256 + tid);
  else if (b < 208) pw_dev(w2,  64,  2,  4096, pk + W2H, pk + W2L, (b-192) * 256 + tid);
  else if (b < 212) pw_dev(w3,  64,  2,  1024, pk + W3H, pk + W3L, (b-208) * 256 + tid);
  else if (b < 308) pw_dev(sw1,384, 12, 24576, pk + S1H, pk + S1L, (b-212) * 256 + tid);
  else if (b < 324) pw_dev(sw2, 64,  2,  4096, pk + S2H, pk + S2L, (b-308) * 256 + tid);
  else if (b < 328) pw_dev(sw3, 64,  2,  1024, pk + S3H, pk + S3L, (b-324) * 256 + tid);
  else if (b < 358) pc1_dev(cw1, pk + C1H, (b-328) * 256 + tid);
  else if (b < 388) pc2_dev(cw2, pk + C2H, (b-358) * 256 + tid);
  else {
    // scan phase 1: 96 blocks = 3 moments x 32 segments of 16 rows.
    const int t = b - 388;
    const int mom = t >> 5, seg = t & 31;
    float* dst = (mom == 0) ? xc : ((mom == 1) ? x2c : x3c);
    const int col = tid;
    if (seg == 0) dst[col] = 0.0f;
    float v[16];
    const int n0 = seg * 16;
#pragma unroll
    for (int k = 0; k < 16; ++k){
      float u = x[(n0 + k) * 256 + col];
      if (mom == 1) u = u * u;
      else if (mom == 2) u = u * u * u;
      v[k] = u;
    }
    float acc = 0.0f;
#pragma unroll
    for (int k = 0; k < 16; ++k){
      acc += v[k];
      dst[(n0 + k + 1) * 256 + col] = acc;
    }
    segTot[t * 256 + col] = acc;
  }
}

// scan phase 2: add exclusive segment offsets.
__global__ __launch_bounds__(256) void scan_fix(
    float* __restrict__ xc, float* __restrict__ x2c, float* __restrict__ x3c,
    const float* __restrict__ segTot)
{
  const int t = blockIdx.x;              // 0..95
  const int mom = t >> 5, seg = t & 31;
  if (seg == 0) return;
  const int col = threadIdx.x;
  float* dst = (mom == 0) ? xc : ((mom == 1) ? x2c : x3c);
  float off = 0.0f;
  for (int s = 0; s < seg; ++s) off += segTot[(mom * 32 + s) * 256 + col];
  const int n0 = seg * 16;
#pragma unroll
  for (int k = 0; k < 16; ++k)
    dst[(n0 + k + 1) * 256 + col] += off;
}

// -------------------- precompute Ya, Yb, Q (tiny GEMMs) --------------------
__global__ __launch_bounds__(256) void pre_gemm(
    const float* __restrict__ x, const float* __restrict__ xc,
    const float* __restrict__ x2c, const float* __restrict__ x3c,
    const short* __restrict__ pk,
    float* __restrict__ Ya, float* __restrict__ Yb, float* __restrict__ Q)
{
  const int tid = threadIdx.x, wave = tid >> 6, lane = tid & 63;
  const int m = lane & 15, quad = lane >> 4;
  if (blockIdx.x < 16){
    const int row0 = blockIdx.x * 64 + wave * 16;
    f4v accA[4], accB[4];
#pragma unroll
    for (int nt = 0; nt < 4; ++nt){
      accA[nt] = (f4v){0.f,0.f,0.f,0.f};
      accB[nt] = (f4v){0.f,0.f,0.f,0.f};
    }
    for (int ks = 0; ks < 4; ++ks){
      const int d0 = ks * 32 + quad * 8;
      s8v ah, al;
      float v[8];
      ld8(x + (row0 + m) * 128 + d0, v);
      cvt8(v, ah, al);
#pragma unroll
      for (int nt = 0; nt < 4; ++nt){
        const int foA = ((nt * 24 + ks) * 64 + lane) << 3;
        const int foB = ((nt * 24 + 4 + ks) * 64 + lane) << 3;
        const s8v bhA = *(const s8v*)(pk + W1H + foA);
        const s8v blA = *(const s8v*)(pk + W1L + foA);
        const s8v bhB = *(const s8v*)(pk + W1H + foB);
        const s8v blB = *(const s8v*)(pk + W1L + foB);
        accA[nt] = MFMA16(ah, bhA, accA[nt], 0, 0, 0);
        accA[nt] = MFMA16(al, bhA, accA[nt], 0, 0, 0);
        accA[nt] = MFMA16(ah, blA, accA[nt], 0, 0, 0);
        accB[nt] = MFMA16(ah, bhB, accB[nt], 0, 0, 0);
        accB[nt] = MFMA16(al, bhB, accB[nt], 0, 0, 0);
        accB[nt] = MFMA16(ah, blB, accB[nt], 0, 0, 0);
      }
    }
#pragma unroll
    for (int nt = 0; nt < 4; ++nt)
#pragma unroll
      for (int reg = 0; reg < 4; ++reg){
        const int r2 = row0 + quad * 4 + reg;
        const int col = nt * 16 + m;
        Ya[r2 * 64 + col] = accA[nt][reg];
        Yb[r2 * 64 + col] = accB[nt][reg];
      }
  } else {
    const int row0 = (blockIdx.x - 16) * 64 + wave * 16;
    f4v acc[4];
#pragma unroll
    for (int nt = 0; nt < 4; ++nt) acc[nt] = (f4v){0.f,0.f,0.f,0.f};
    int rr = row0 + m; if (rr > 1025) rr = 1025;
#pragma unroll
    for (int c = 0; c < 3; ++c){
      const float* src = (c == 0) ? xc : ((c == 1) ? x2c : x3c);
      for (int ks = 0; ks < 4; ++ks){
        const int d0 = ks * 32 + quad * 8;
        s8v ah, al;
        float v[8];
        ld8(src + rr * 128 + d0, v);
        cvt8(v, ah, al);
#pragma unroll
        for (int nt = 0; nt < 4; ++nt){
          const int fo = ((nt * 24 + (c + 3) * 4 + ks) * 64 + lane) << 3;
          const s8v bh = *(const s8v*)(pk + W1H + fo);
          const s8v bl = *(const s8v*)(pk + W1L + fo);
          acc[nt] = MFMA16(ah, bh, acc[nt], 0, 0, 0);
          acc[nt] = MFMA16(al, bh, acc[nt], 0, 0, 0);
          acc[nt] = MFMA16(ah, bl, acc[nt], 0, 0, 0);
        }
      }
    }
#pragma unroll
    for (int nt = 0; nt < 4; ++nt)
#pragma unroll
      for (int reg = 0; reg < 4; ++reg){
        const int r2 = row0 + quad * 4 + reg;
        if (r2 < 1026) Q[r2 * 64 + nt * 16 + m] = acc[nt][reg];
      }
  }
}

// ---------------- pairwise MLP (blocks 0..2051) + skip (2052..2067) --------
// pair: pure bf16-RTN, hh-only (16KB LDS). skip: hi in hh[w][0..1023],
// lo in hh[w][1024..2047]. launch_bounds(256,6): VGPR cap ~85 > 64-reg
// natural live set (r11's (256,8) cap of 64 forced VGPR=32 -> spills).
__global__ __launch_bounds__(256, 6) void pair_mlp(
    const float* __restrict__ x, const short* __restrict__ pk,
    const float* __restrict__ Ya, const float* __restrict__ Yb,
    const float* __restrict__ Q,
    const float* __restrict__ b1, const float* __restrict__ b2,
    const float* __restrict__ b3,
    const float* __restrict__ sb1, const float* __restrict__ sb2,
    const float* __restrict__ sb3,
    float* __restrict__ Sd, float* __restrict__ outK)
{
  __shared__ __attribute__((aligned(16))) short hh[4][2048];
  const int tid = threadIdx.x;
  const int wave = tid >> 6, lane = tid & 63;
  const int m = lane & 15, quad = lane >> 4;

  if (blockIdx.x >= 2052){
    // ------------------------- skip MLP path (hi/lo) -----------------------
    const int rowBase = (blockIdx.x - 2052) * 64 + wave * 16;
    int r = rowBase + m; if (r > 1021) r = 1021;
    const int nidx = r >> 1, bb = r & 1;
    const int oi = (nidx * 2 + bb) * 128, oj = ((nidx + 1) * 2 + bb) * 128;

    f4v acc[4];
#pragma unroll
    for (int nt = 0; nt < 4; ++nt) acc[nt] = (f4v){0.f,0.f,0.f,0.f};

    for (int d4 = 0; d4 < 4; ++d4){
      const int d0 = d4 * 32 + quad * 8;
      float vi[8], vj[8];
      ld8(x + oi + d0, vi); ld8(x + oj + d0, vj);
#pragma unroll
      for (int cc = 0; cc < 3; ++cc){
        const int c = (cc == 0) ? 2 : (cc - 1);
        s8v ah, al;
        if (c == 2){
          float vp[8];
#pragma unroll
          for (int t = 0; t < 8; ++t) vp[t] = vi[t] * vj[t];
          cvt8(vp, ah, al);
        } else if (c == 0) cvt8(vi, ah, al);
        else               cvt8(vj, ah, al);
        const int ks = c * 4 + d4;
#pragma unroll
        for (int nt = 0; nt < 4; ++nt){
          const int fo = ((nt * 12 + ks) * 64 + lane) << 3;
          const s8v bh = *(const s8v*)(pk + S1H + fo);
          const s8v bl = *(const s8v*)(pk + S1L + fo);
          acc[nt] = MFMA16(ah, bh, acc[nt], 0, 0, 0);
          acc[nt] = MFMA16(al, bh, acc[nt], 0, 0, 0);
          acc[nt] = MFMA16(ah, bl, acc[nt], 0, 0, 0);
        }
      }
    }
#pragma unroll
    for (int nt = 0; nt < 4; ++nt){
      const float bias = sb1[nt * 16 + m];
#pragma unroll
      for (int reg = 0; reg < 4; ++reg){
        const float v = gelu_f(acc[nt][reg] + bias);
        const int idx = (quad * 4 + reg) * 64 + ((nt * 16 + m) ^ (quad << 4));
        const unsigned uv = __float_as_uint(v);
        hh[wave][idx] = (short)(uv >> 16);
        const float lo = v - __uint_as_float(uv & 0xFFFF0000u);
        hh[wave][1024 + idx] = (short)(__float_as_uint(lo) >> 16);
      }
    }
    s8v a2h[2], a2l[2];
#pragma unroll
    for (int k2 = 0; k2 < 2; ++k2){
      const int off = m * 64 + ((k2 * 32 + quad * 8) ^ ((m >> 2) << 4));
      a2h[k2] = *(const s8v*)&hh[wave][off];
      a2l[k2] = *(const s8v*)&hh[wave][1024 + off];
    }
    f4v acc2[4];
#pragma unroll
    for (int nt = 0; nt < 4; ++nt) acc2[nt] = (f4v){0.f,0.f,0.f,0.f};
#pragma unroll
    for (int k2 = 0; k2 < 2; ++k2)
#pragma unroll
      for (int nt = 0; nt < 4; ++nt){
        const int fo = ((nt * 2 + k2) * 64 + lane) << 3;
        const s8v bh = *(const s8v*)(pk + S2H + fo);
        const s8v bl = *(const s8v*)(pk + S2L + fo);
        acc2[nt] = MFMA16(a2h[k2], bh, acc2[nt], 0, 0, 0);
        acc2[nt] = MFMA16(a2l[k2], bh, acc2[nt], 0, 0, 0);
        acc2[nt] = MFMA16(a2h[k2], bl, acc2[nt], 0, 0, 0);
      }
#pragma unroll
    for (int nt = 0; nt < 4; ++nt){
      const float bias = sb2[nt * 16 + m];
#pragma unroll
      for (int reg = 0; reg < 4; ++reg){
        const float v = gelu_f(acc2[nt][reg] + bias);
        const int idx = (quad * 4 + reg) * 64 + ((nt * 16 + m) ^ (quad << 4));
        const unsigned uv = __float_as_uint(v);
        hh[wave][idx] = (short)(uv >> 16);
        const float lo = v - __uint_as_float(uv & 0xFFFF0000u);
        hh[wave][1024 + idx] = (short)(__float_as_uint(lo) >> 16);
      }
    }
    s8v a3h[2], a3l[2];
#pragma unroll
    for (int k3 = 0; k3 < 2; ++k3){
      const int off = m * 64 + ((k3 * 32 + quad * 8) ^ ((m >> 2) << 4));
      a3h[k3] = *(const s8v*)&hh[wave][off];
      a3l[k3] = *(const s8v*)&hh[wave][1024 + off];
    }
    f4v acc3 = (f4v){0.f,0.f,0.f,0.f};
#pragma unroll
    for (int k3 = 0; k3 < 2; ++k3){
      const int fo = (k3 * 64 + lane) << 3;
      const s8v bh = *(const s8v*)(pk + S3H + fo);
      const s8v bl = *(const s8v*)(pk + S3L + fo);
      acc3 = MFMA16(a3h[k3], bh, acc3, 0, 0, 0);
      acc3 = MFMA16(a3l[k3], bh, acc3, 0, 0, 0);
      acc3 = MFMA16(a3h[k3], bl, acc3, 0, 0, 0);
    }
    const float bias3 = sb3[m];
#pragma unroll
    for (int reg = 0; reg < 4; ++reg){
      const int R = rowBase + quad * 4 + reg;
      if (R < 1022) outK[R * 16 + m] = acc3[reg] + bias3;
    }
    return;
  }

  // --------------------------- pair path (pure bf16) -----------------------
  const int rowBase = blockIdx.x * 128 + wave * 32;
  int oi[2], oj[2];
  int qa2[2][2], qb2[2][2];
  float invLr[2][2];
#pragma unroll
  for (int s = 0; s < 2; ++s){
    {
      const int r = rowBase + s * 16 + m;
      const int p = r >> 1, b = r & 1;
      const int i = inv_tri(p), j = p - i * (i + 1) / 2;
      oi[s] = (i * 2 + b) * 128;
      oj[s] = (j * 2 + b) * 128;
    }
    {
      const int p0 = (rowBase + s * 16 + quad * 4) >> 1;
      const int i0 = inv_tri(p0), j0 = p0 - i0 * (i0 + 1) / 2;
      qa2[s][0] = (i0 + 1) * 128; qb2[s][0] = j0 * 128;
      invLr[s][0] = 1.0f / (float)(i0 - j0 + 1);
      int i1 = i0, j1 = j0 + 1;
      if (j1 > i1){ i1 = i0 + 1; j1 = 0; }
      qa2[s][1] = (i1 + 1) * 128; qb2[s][1] = j1 * 128;
      invLr[s][1] = 1.0f / (float)(i1 - j1 + 1);
    }
  }

  f4v acc[2][4];
#pragma unroll
  for (int s = 0; s < 2; ++s)
#pragma unroll
    for (int nt = 0; nt < 4; ++nt) acc[s][nt] = (f4v){0.f,0.f,0.f,0.f};

  // layer-1 Hadamard GEMM, K=128, bf16-RTN single MFMA
  for (int d4 = 0; d4 < 4; ++d4){
    const int d0 = d4 * 32 + quad * 8;
    s8v ah[2];
#pragma unroll
    for (int s = 0; s < 2; ++s){
      float vi[8], vj[8];
      ld8(x + oi[s] + d0, vi); ld8(x + oj[s] + d0, vj);
#pragma unroll
      for (int t = 0; t < 8; ++t) vi[t] *= vj[t];
      cvt8r(vi, ah[s]);
    }
#pragma unroll
    for (int nt = 0; nt < 4; ++nt){
      const int fo = ((nt * 24 + 8 + d4) * 64 + lane) << 3;
      const s8v bh = *(const s8v*)(pk + W1H + fo);
#pragma unroll
      for (int s = 0; s < 2; ++s)
        acc[s][nt] = MFMA16(ah[s], bh, acc[s][nt], 0, 0, 0);
    }
  }
  // epilogue 1: + Ya[i] + Yb[j] + invL*(Q[i+1]-Q[j]) + b1, gelu -> LDS (RTN)
#pragma unroll
  for (int s = 0; s < 2; ++s)
#pragma unroll
    for (int nt = 0; nt < 4; ++nt){
      const int col = nt * 16 + m;
      const float bias = b1[col];
#pragma unroll
      for (int reg = 0; reg < 4; ++reg){
        const int k = reg >> 1, bb = reg & 1;
        const int off = bb * 64 + col;
        const float add = Ya[qa2[s][k] - 128 + off] + Yb[qb2[s][k] + off]
                        + invLr[s][k] * (Q[qa2[s][k] + off] - Q[qb2[s][k] + off]);
        const float v = gelu_f(acc[s][nt][reg] + bias + add);
        const int idx = (s * 16 + quad * 4 + reg) * 64 + ((nt * 16 + m) ^ (quad << 4));
        hh[wave][idx] = (short)f2bf(v);
      }
    }
  s8v a2h[2][2];
#pragma unroll
  for (int s = 0; s < 2; ++s)
#pragma unroll
    for (int k2 = 0; k2 < 2; ++k2){
      const int off = (s * 16 + m) * 64 + ((k2 * 32 + quad * 8) ^ ((m >> 2) << 4));
      a2h[s][k2] = *(const s8v*)&hh[wave][off];
    }
  // layer 2 (bf16)
  f4v acc2[2][4];
#pragma unroll
  for (int s = 0; s < 2; ++s)
#pragma unroll
    for (int nt = 0; nt < 4; ++nt) acc2[s][nt] = (f4v){0.f,0.f,0.f,0.f};
#pragma unroll
  for (int k2 = 0; k2 < 2; ++k2)
#pragma unroll
    for (int nt = 0; nt < 4; ++nt){
      const int fo = ((nt * 2 + k2) * 64 + lane) << 3;
      const s8v bh = *(const s8v*)(pk + W2H + fo);
#pragma unroll
      for (int s = 0; s < 2; ++s)
        acc2[s][nt] = MFMA16(a2h[s][k2], bh, acc2[s][nt], 0, 0, 0);
    }
#pragma unroll
  for (int s = 0; s < 2; ++s)
#pragma unroll
    for (int nt = 0; nt < 4; ++nt){
      const float bias = b2[nt * 16 + m];
#pragma unroll
      for (int reg = 0; reg < 4; ++reg){
        const float v = gelu_f(acc2[s][nt][reg] + bias);
        const int idx = (s * 16 + quad * 4 + reg) * 64 + ((nt * 16 + m) ^ (quad << 4));
        hh[wave][idx] = (short)f2bf(v);
      }
    }
  s8v a3h[2][2];
#pragma unroll
  for (int s = 0; s < 2; ++s)
#pragma unroll
    for (int k3 = 0; k3 < 2; ++k3){
      const int off = (s * 16 + m) * 64 + ((k3 * 32 + quad * 8) ^ ((m >> 2) << 4));
      a3h[s][k3] = *(const s8v*)&hh[wave][off];
    }
  // layer 3 (bf16)
  f4v acc3[2];
  acc3[0] = (f4v){0.f,0.f,0.f,0.f};
  acc3[1] = (f4v){0.f,0.f,0.f,0.f};
#pragma unroll
  for (int k3 = 0; k3 < 2; ++k3){
    const int fo = (k3 * 64 + lane) << 3;
    const s8v bh = *(const s8v*)(pk + W3H + fo);
#pragma unroll
    for (int s = 0; s < 2; ++s)
      acc3[s] = MFMA16(a3h[s][k3], bh, acc3[s], 0, 0, 0);
  }
  const float bias3 = b3[m];
#pragma unroll
  for (int s = 0; s < 2; ++s)
#pragma unroll
    for (int reg = 0; reg < 4; ++reg){
      const int k = reg >> 1, bb = reg & 1;
      const int i = (qa2[s][k] >> 7) - 1, j = qb2[s][k] >> 7;
      Sd[((i * 512 + j) * 2 + bb) * 16 + m] = acc3[s][reg] + bias3;
    }
}

// ------------- MFMA fused conv1(pad2)+gelu+conv2+len-scale -----------------
// pure bf16-RTN; sT 400x24, hT 324x24 shorts -> 34.8KB LDS, 4 blocks/CU.
__global__ __launch_bounds__(256) void conv_mfma(
    const float* __restrict__ Sd, const short* __restrict__ pk,
    const float* __restrict__ cb1, const float* __restrict__ cb2,
    float* __restrict__ out)
{
  __shared__ __attribute__((aligned(16))) short sT[9600];   // 400 px * 24
  __shared__ __attribute__((aligned(16))) short hT[7776];   // 324 px * 24

  const int tid = threadIdx.x;
  const int X0 = blockIdx.x * 16, Y0 = blockIdx.y * 16, bb = blockIdx.z;
  const int lane = tid & 63, wave = tid >> 6;
  const int mcol = lane & 15, quad = lane >> 4;
  const int tq = quad >> 1, icl0 = (quad & 1) * 8;

  for (int e = tid; e < 1600; e += 256){
    const int q = e & 3, p = e >> 2;
    const int row = p / 20, col = p % 20;
    const int gy = Y0 - 2 + row, gx = X0 - 2 + col;
    float4 v = make_float4(0.f, 0.f, 0.f, 0.f);
    if (gy >= 0 && gy < 512 && gx >= 0 && gx <= gy)
      v = *(const float4*)(Sd + (((gy * 512 + gx) * 2 + bb) * 16 + q * 4));
    int2 pkd;
    pkd.x = ((unsigned)f2bf(v.y) << 16) | (unsigned)f2bf(v.x);
    pkd.y = ((unsigned)f2bf(v.w) << 16) | (unsigned)f2bf(v.z);
    *(int2*)&sT[p * 24 + q * 4] = pkd;
  }
  __syncthreads();

  int base1[6];
#pragma unroll
  for (int it = 0; it < 6; ++it){
    int p = (wave * 6 + it) * 16 + mcol; if (p > 323) p = 323;
    const int u = p / 18, v = p - u * 18;
    base1[it] = (u * 20 + v) * 24 + icl0;
  }
  int base2[4];
#pragma unroll
  for (int t2 = 0; t2 < 4; ++t2){
    const int p = (wave * 4 + t2) * 16 + mcol;
    base2[t2] = (p >> 4) * 18 + (p & 15);
  }

  const float bias2 = cb2[mcol];
  f4v acc2[4];
#pragma unroll
  for (int t2 = 0; t2 < 4; ++t2) acc2[t2] = (f4v){0.f,0.f,0.f,0.f};

  for (int chunk = 0; chunk < 3; ++chunk){
    f4v c1[6];
#pragma unroll
    for (int it = 0; it < 6; ++it) c1[it] = (f4v){0.f,0.f,0.f,0.f};
    for (int ks = 0; ks < 5; ++ks){
      int tap = ks * 2 + tq; if (tap > 8) tap = 8;   // tap9 -> B is zero
      const int ky = tap / 3, kx = tap - ky * 3;
      const int off1 = (ky * 20 + kx) * 24;
      const int fo = ((chunk * 5 + ks) * 64 + lane) << 3;
      const s8v b1h = *(const s8v*)(pk + C1H + fo);
#pragma unroll
      for (int it = 0; it < 6; ++it){
        const s8v ah = *(const s8v*)&sT[base1[it] + off1];
        c1[it] = MFMA16(ah, b1h, c1[it], 0, 0, 0);
      }
    }
    const float bias1 = cb1[chunk * 16 + mcol];
#pragma unroll
    for (int it = 0; it < 6; ++it){
      const int pb = (wave * 6 + it) * 16 + quad * 4;
#pragma unroll
      for (int reg = 0; reg < 4; ++reg){
        const int p = pb + reg;
        if (p < 324)
          hT[p * 24 + mcol] = (short)f2bf(gelu_f(c1[it][reg] + bias1));
      }
    }
    __syncthreads();
    for (int ks = 0; ks < 5; ++ks){
      int tap = ks * 2 + tq; if (tap > 8) tap = 8;
      const int ky = tap / 3, kx = tap - ky * 3;
      const int off2 = ky * 18 + kx;
      const int fo = ((chunk * 5 + ks) * 64 + lane) << 3;
      const s8v b2h = *(const s8v*)(pk + C2H + fo);
#pragma unroll
      for (int t2 = 0; t2 < 4; ++t2){
        const s8v ah = *(const s8v*)&hT[(base2[t2] + off2) * 24 + icl0];
        acc2[t2] = MFMA16(ah, b2h, acc2[t2], 0, 0, 0);
      }
    }
    __syncthreads();
  }
#pragma unroll
  for (int t2 = 0; t2 < 4; ++t2){
#pragma unroll
    for (int reg = 0; reg < 4; ++reg){
      const int p = (wave * 4 + t2) * 16 + quad * 4 + reg;
      const int Y = Y0 + (p >> 4), X = X0 + (p & 15);
      int l = Y - X; if (l < 0) l = -l; if (l < 1) l = 1;
      out[((Y * 512 + X) * 2 + bb) * 16 + mcol] = (acc2[t2][reg] + bias2) * (float)l;
    }
  }
}

// ---------------------------------------------------------------------------
extern "C" void kernel_launch(void* const* d_in, const int* in_sizes, int n_in,
                              void* d_out, int out_size, void* d_ws, size_t ws_size,
                              hipStream_t stream)
{
  (void)in_sizes; (void)n_in; (void)out_size; (void)ws_size;
  const float* x   = (const float*)d_in[0];
  const float* w1  = (const float*)d_in[1];
  const float* b1  = (const float*)d_in[2];
  const float* w2  = (const float*)d_in[3];
  const float* b2  = (const float*)d_in[4];
  const float* w3  = (const float*)d_in[5];
  const float* b3  = (const float*)d_in[6];
  const float* sw1 = (const float*)d_in[7];
  const float* sb1 = (const float*)d_in[8];
  const float* sw2 = (const float*)d_in[9];
  const float* sb2 = (const float*)d_in[10];
  const float* sw3 = (const float*)d_in[11];
  const float* sb3 = (const float*)d_in[12];
  const float* cw1 = (const float*)d_in[13];
  const float* cb1 = (const float*)d_in[14];
  const float* cw2 = (const float*)d_in[15];
  const float* cb2 = (const float*)d_in[16];

  float* ws  = (float*)d_ws;
  float* xc  = ws;
  float* x2c = ws + 131328;
  float* x3c = ws + 262656;
  float* Sd  = ws + 393984;
  short* pk  = (short*)(ws + 8782592);
  float* Ya  = ws + 8881920;
  float* Yb  = ws + 8947456;
  float* Q   = ws + 9012992;
  float* segTot = ws + 9078656;
  float* outS = (float*)d_out;
  float* outK = outS + 8388608;

  setup_fused<<<484, 256, 0, stream>>>(x, w1, w2, w3, sw1, sw2, sw3, cw1, cw2,
                                       xc, x2c, x3c, pk, segTot);
  scan_fix<<<96, 256, 0, stream>>>(xc, x2c, x3c, segTot);
  pre_gemm<<<33, 256, 0, stream>>>(x, xc, x2c, x3c, pk, Ya, Yb, Q);
  pair_mlp<<<2068, 256, 0, stream>>>(x, pk, Ya, Yb, Q, b1, b2, b3,
                                     sb1, sb2, sb3, Sd, outK);
  conv_mfma<<<dim3(32, 32, 2), 256, 0, stream>>>(Sd, pk, cb1, cb2, outS);
}

// Round 13
// 232.662 us; speedup vs baseline: 1.1776x; 1.0428x over previous
//
#include <hip/hip_runtime.h>
#include <math.h>

// ---------------------------------------------------------------------------
// PairwiseFeatureBatch: N=512, B=2, D=128, O=16, H=64, CH=48
//   out0: S [512,512,2,16] f32 ; out1: S_skip [511,2,16] f32
// ws (floats): xc@0 x2c@131328 x3c@262656 Sd@393984 pk@8782592(short area)
//              Ya@8881920 Yb@8947456 Q@9012992 segTot@9078656 Kc@9103232
// 5 dispatches: setup_fused -> scan_fix -> pre_gemm -> pair_mlp -> conv_mfma
// r13: (a) pair launch_bounds (256,6)->(256,5): r12 still had ~17MB residual
//      spill writes (VGPR forced to 40); cap 102 lets the natural 64-reg set
//      allocate spill-free. (b) conv constant-block fast path: for X0>=Y0+32
//      the whole receptive field is above the diagonal (S=0) -> out =
//      lenBA*K[oc], K = cb2 + sum w2*gelu(cb1) precomputed in setup. 45% of
//      conv blocks skip staging + MFMA entirely.
// ---------------------------------------------------------------------------

typedef __attribute__((ext_vector_type(8))) short s8v;
typedef __attribute__((ext_vector_type(4))) float f4v;

union U8 { int i[4]; s8v s; };

__device__ __forceinline__ unsigned short f2bf(float f){
  unsigned u = __float_as_uint(f);
  unsigned r = u + 0x7FFFu + ((u >> 16) & 1u);
  return (unsigned short)(r >> 16);
}
__device__ __forceinline__ float bf2f(unsigned short h){
  return __uint_as_float(((unsigned)h) << 16);
}
// exact-GELU via branch-free erf approx (A&S 7.1.26, |err|<=1.5e-7)
__device__ __forceinline__ float gelu_f(float v){
  const float z  = v * 0.7071067811865476f;
  const float az = __builtin_fabsf(z);
  const float t  = __builtin_amdgcn_rcpf(1.0f + 0.3275911f * az);
  float p = 1.061405429f;
  p = p * t - 1.453152027f;
  p = p * t + 1.421413741f;
  p = p * t - 0.284496736f;
  p = p * t + 0.254829592f;
  p = p * t;
  const float e  = __expf(-az * az);
  const float ea = 1.0f - p * e;
  const float er = __uint_as_float((__float_as_uint(z) & 0x80000000u) | __float_as_uint(ea));
  return 0.5f * v * (1.0f + er);
}
__device__ __forceinline__ int inv_tri(int p){
  float t = sqrtf(8.0f * (float)p + 1.0f);
  int i = (int)((t - 1.0f) * 0.5f);
  while ((i + 1) * (i + 2) / 2 <= p) ++i;
  while (i * (i + 1) / 2 > p) --i;
  return i;
}
// truncation hi/lo split, v_perm packing (hi exact-residual: lo = f - hi)
__device__ __forceinline__ void cvt8(const float v[8], s8v& hi, s8v& lo){
  U8 H, L;
#pragma unroll
  for (int t = 0; t < 4; ++t){
    const unsigned a = __float_as_uint(v[2*t]);
    const unsigned b = __float_as_uint(v[2*t+1]);
    H.i[t] = (int)__builtin_amdgcn_perm(b, a, 0x07060302u);
    const float la = v[2*t]   - __uint_as_float(a & 0xFFFF0000u);
    const float lb = v[2*t+1] - __uint_as_float(b & 0xFFFF0000u);
    L.i[t] = (int)__builtin_amdgcn_perm(__float_as_uint(lb), __float_as_uint(la), 0x07060302u);
  }
  hi = H.s; lo = L.s;
}
// RTN bf16 pack (no residual)
__device__ __forceinline__ void cvt8r(const float v[8], s8v& hi){
  U8 H;
#pragma unroll
  for (int t = 0; t < 4; ++t)
    H.i[t] = ((unsigned)f2bf(v[2*t+1]) << 16) | (unsigned)f2bf(v[2*t]);
  hi = H.s;
}
__device__ __forceinline__ void ld8(const float* p, float v[8]){
  const float4 a0 = *(const float4*)p;
  const float4 a1 = *(const float4*)(p + 4);
  v[0]=a0.x; v[1]=a0.y; v[2]=a0.z; v[3]=a0.w;
  v[4]=a1.x; v[5]=a1.y; v[6]=a1.z; v[7]=a1.w;
}

// packed-area short offsets
#define W1H 0
#define W1L 49152
#define W2H 98304
#define W2L 102400
#define W3H 106496
#define W3L 107520
#define S1H 108544
#define S1L 133120
#define S2H 157696
#define S2L 161792
#define S3H 165888
#define S3L 166912
#define C1H 167936
#define C1L 175616
#define C2H 183296
#define C2L 190976

#define MFMA16 __builtin_amdgcn_mfma_f32_16x16x32_bf16

// ----------------------- fused setup (packs + scan phase 1 + K) ------------
__device__ __forceinline__ void pw_dev(const float* __restrict__ W,
    int K, int KS, int nEl, short* __restrict__ hiD, short* __restrict__ loD, int pos)
{
  if (pos >= nEl) return;
  const int j = pos & 7, lane = (pos >> 3) & 63, t2 = pos >> 9;
  const int ks = t2 % KS, nt = t2 / KS;
  const int n = nt * 16 + (lane & 15);
  const int k = ks * 32 + ((lane >> 4) & 3) * 8 + j;
  const float v = W[n * K + k];
  const unsigned short h = f2bf(v);
  hiD[pos] = (short)h;
  loD[pos] = (short)f2bf(v - bf2f(h));
}
__device__ __forceinline__ void pc1_dev(const float* __restrict__ W,
    short* __restrict__ hiD, int pos)
{
  if (pos >= 7680) return;
  const int j = pos & 7, lane = (pos >> 3) & 63, t2 = pos >> 9;
  const int ks = t2 % 5, chunk = t2 / 5;
  const int n = chunk * 16 + (lane & 15);
  const int k = ks * 32 + ((lane >> 4) & 3) * 8 + j;
  const int tap = k >> 4, ic = k & 15;
  const float v = (tap < 9) ? W[(n * 16 + ic) * 9 + tap] : 0.0f;
  hiD[pos] = (short)f2bf(v);
}
__device__ __forceinline__ void pc2_dev(const float* __restrict__ W,
    short* __restrict__ hiD, int pos)
{
  if (pos >= 7680) return;
  const int j = pos & 7, lane = (pos >> 3) & 63, t2 = pos >> 9;
  const int ks = t2 % 5, chunk = t2 / 5;
  const int n = lane & 15;
  const int k = ks * 32 + ((lane >> 4) & 3) * 8 + j;
  const int tap = k >> 4, ic = chunk * 16 + (k & 15);
  const float v = (tap < 9) ? W[(n * 48 + ic) * 9 + tap] : 0.0f;
  hiD[pos] = (short)f2bf(v);
}

__global__ __launch_bounds__(256) void setup_fused(
    const float* __restrict__ x,
    const float* __restrict__ w1, const float* __restrict__ w2,
    const float* __restrict__ w3, const float* __restrict__ sw1,
    const float* __restrict__ sw2, const float* __restrict__ sw3,
    const float* __restrict__ cw1, const float* __restrict__ cw2,
    const float* __restrict__ cb1, const float* __restrict__ cb2,
    float* __restrict__ xc, float* __restrict__ x2c, float* __restrict__ x3c,
    short* __restrict__ pk, float* __restrict__ segTot, float* __restrict__ Kc)
{
  const int b = blockIdx.x, tid = threadIdx.x;
  if (b < 192)      pw_dev(w1, 768, 24, 49152, pk + W1H, pk + W1L, b * 256 + tid);
  else if (b < 208) pw_dev(w2,  64,  2,  4096, pk + W2H, pk + W2L, (b-192) * 256 + tid);
  else if (b < 212) pw_dev(w3,  64,  2,  1024, pk + W3H, pk + W3L, (b-208) * 256 + tid);
  else if (b < 308) pw_dev(sw1,384, 12, 24576, pk + S1H, pk + S1L, (b-212) * 256 + tid);
  else if (b < 324) pw_dev(sw2, 64,  2,  4096, pk + S2H, pk + S2L, (b-308) * 256 + tid);
  else if (b < 328) pw_dev(sw3, 64,  2,  1024, pk + S3H, pk + S3L, (b-324) * 256 + tid);
  else if (b < 358) pc1_dev(cw1, pk + C1H, (b-328) * 256 + tid);
  else if (b < 388) pc2_dev(cw2, pk + C2H, (b-358) * 256 + tid);
  else if (b < 484) {
    // scan phase 1: 96 blocks = 3 moments x 32 segments of 16 rows.
    const int t = b - 388;
    const int mom = t >> 5, seg = t & 31;
    float* dst = (mom == 0) ? xc : ((mom == 1) ? x2c : x3c);
    const int col = tid;
    if (seg == 0) dst[col] = 0.0f;
    float v[16];
    const int n0 = seg * 16;
#pragma unroll
    for (int k = 0; k < 16; ++k){
      float u = x[(n0 + k) * 256 + col];
      if (mom == 1) u = u * u;
      else if (mom == 2) u = u * u * u;
      v[k] = u;
    }
    float acc = 0.0f;
#pragma unroll
    for (int k = 0; k < 16; ++k){
      acc += v[k];
      dst[(n0 + k + 1) * 256 + col] = acc;
    }
    segTot[t * 256 + col] = acc;
  } else {
    // K[oc] = cb2 + sum_{cl,tap} bf16(w2)*bf16(gelu(cb1[cl]))  (conv const)
    if (tid < 16){
      float K = cb2[tid];
      for (int cl = 0; cl < 48; ++cl){
        const float g = bf2f(f2bf(gelu_f(cb1[cl])));
#pragma unroll
        for (int tap = 0; tap < 9; ++tap){
          const float w = bf2f(f2bf(cw2[(tid * 48 + cl) * 9 + tap]));
          K += w * g;
        }
      }
      Kc[tid] = K;
    }
  }
}

// scan phase 2: add exclusive segment offsets.
__global__ __launch_bounds__(256) void scan_fix(
    float* __restrict__ xc, float* __restrict__ x2c, float* __restrict__ x3c,
    const float* __restrict__ segTot)
{
  const int t = blockIdx.x;              // 0..95
  const int mom = t >> 5, seg = t & 31;
  if (seg == 0) return;
  const int col = threadIdx.x;
  float* dst = (mom == 0) ? xc : ((mom == 1) ? x2c : x3c);
  float off = 0.0f;
  for (int s = 0; s < seg; ++s) off += segTot[(mom * 32 + s) * 256 + col];
  const int n0 = seg * 16;
#pragma unroll
  for (int k = 0; k < 16; ++k)
    dst[(n0 + k + 1) * 256 + col] += off;
}

// -------------------- precompute Ya, Yb, Q (tiny GEMMs) --------------------
__global__ __launch_bounds__(256) void pre_gemm(
    const float* __restrict__ x, const float* __restrict__ xc,
    const float* __restrict__ x2c, const float* __restrict__ x3c,
    const short* __restrict__ pk,
    float* __restrict__ Ya, float* __restrict__ Yb, float* __restrict__ Q)
{
  const int tid = threadIdx.x, wave = tid >> 6, lane = tid & 63;
  const int m = lane & 15, quad = lane >> 4;
  if (blockIdx.x < 16){
    const int row0 = blockIdx.x * 64 + wave * 16;
    f4v accA[4], accB[4];
#pragma unroll
    for (int nt = 0; nt < 4; ++nt){
      accA[nt] = (f4v){0.f,0.f,0.f,0.f};
      accB[nt] = (f4v){0.f,0.f,0.f,0.f};
    }
    for (int ks = 0; ks < 4; ++ks){
      const int d0 = ks * 32 + quad * 8;
      s8v ah, al;
      float v[8];
      ld8(x + (row0 + m) * 128 + d0, v);
      cvt8(v, ah, al);
#pragma unroll
      for (int nt = 0; nt < 4; ++nt){
        const int foA = ((nt * 24 + ks) * 64 + lane) << 3;
        const int foB = ((nt * 24 + 4 + ks) * 64 + lane) << 3;
        const s8v bhA = *(const s8v*)(pk + W1H + foA);
        const s8v blA = *(const s8v*)(pk + W1L + foA);
        const s8v bhB = *(const s8v*)(pk + W1H + foB);
        const s8v blB = *(const s8v*)(pk + W1L + foB);
        accA[nt] = MFMA16(ah, bhA, accA[nt], 0, 0, 0);
        accA[nt] = MFMA16(al, bhA, accA[nt], 0, 0, 0);
        accA[nt] = MFMA16(ah, blA, accA[nt], 0, 0, 0);
        accB[nt] = MFMA16(ah, bhB, accB[nt], 0, 0, 0);
        accB[nt] = MFMA16(al, bhB, accB[nt], 0, 0, 0);
        accB[nt] = MFMA16(ah, blB, accB[nt], 0, 0, 0);
      }
    }
#pragma unroll
    for (int nt = 0; nt < 4; ++nt)
#pragma unroll
      for (int reg = 0; reg < 4; ++reg){
        const int r2 = row0 + quad * 4 + reg;
        const int col = nt * 16 + m;
        Ya[r2 * 64 + col] = accA[nt][reg];
        Yb[r2 * 64 + col] = accB[nt][reg];
      }
  } else {
    const int row0 = (blockIdx.x - 16) * 64 + wave * 16;
    f4v acc[4];
#pragma unroll
    for (int nt = 0; nt < 4; ++nt) acc[nt] = (f4v){0.f,0.f,0.f,0.f};
    int rr = row0 + m; if (rr > 1025) rr = 1025;
#pragma unroll
    for (int c = 0; c < 3; ++c){
      const float* src = (c == 0) ? xc : ((c == 1) ? x2c : x3c);
      for (int ks = 0; ks < 4; ++ks){
        const int d0 = ks * 32 + quad * 8;
        s8v ah, al;
        float v[8];
        ld8(src + rr * 128 + d0, v);
        cvt8(v, ah, al);
#pragma unroll
        for (int nt = 0; nt < 4; ++nt){
          const int fo = ((nt * 24 + (c + 3) * 4 + ks) * 64 + lane) << 3;
          const s8v bh = *(const s8v*)(pk + W1H + fo);
          const s8v bl = *(const s8v*)(pk + W1L + fo);
          acc[nt] = MFMA16(ah, bh, acc[nt], 0, 0, 0);
          acc[nt] = MFMA16(al, bh, acc[nt], 0, 0, 0);
          acc[nt] = MFMA16(ah, bl, acc[nt], 0, 0, 0);
        }
      }
    }
#pragma unroll
    for (int nt = 0; nt < 4; ++nt)
#pragma unroll
      for (int reg = 0; reg < 4; ++reg){
        const int r2 = row0 + quad * 4 + reg;
        if (r2 < 1026) Q[r2 * 64 + nt * 16 + m] = acc[nt][reg];
      }
  }
}

// ---------------- pairwise MLP (blocks 0..2051) + skip (2052..2067) --------
// pair: pure bf16-RTN, hh-only (16KB LDS). skip: hi in hh[w][0..1023],
// lo in hh[w][1024..2047]. launch_bounds(256,5): cap 102 VGPR > 64-reg
// natural set -> spill-free (r12's (256,6) cap still forced VGPR=40 +
// ~17MB scratch); VGPR 64 itself allows 8 waves/SIMD residency.
__global__ __launch_bounds__(256, 5) void pair_mlp(
    const float* __restrict__ x, const short* __restrict__ pk,
    const float* __restrict__ Ya, const float* __restrict__ Yb,
    const float* __restrict__ Q,
    const float* __restrict__ b1, const float* __restrict__ b2,
    const float* __restrict__ b3,
    const float* __restrict__ sb1, const float* __restrict__ sb2,
    const float* __restrict__ sb3,
    float* __restrict__ Sd, float* __restrict__ outK)
{
  __shared__ __attribute__((aligned(16))) short hh[4][2048];
  const int tid = threadIdx.x;
  const int wave = tid >> 6, lane = tid & 63;
  const int m = lane & 15, quad = lane >> 4;

  if (blockIdx.x >= 2052){
    // ------------------------- skip MLP path (hi/lo) -----------------------
    const int rowBase = (blockIdx.x - 2052) * 64 + wave * 16;
    int r = rowBase + m; if (r > 1021) r = 1021;
    const int nidx = r >> 1, bb = r & 1;
    const int oi = (nidx * 2 + bb) * 128, oj = ((nidx + 1) * 2 + bb) * 128;

    f4v acc[4];
#pragma unroll
    for (int nt = 0; nt < 4; ++nt) acc[nt] = (f4v){0.f,0.f,0.f,0.f};

    for (int d4 = 0; d4 < 4; ++d4){
      const int d0 = d4 * 32 + quad * 8;
      float vi[8], vj[8];
      ld8(x + oi + d0, vi); ld8(x + oj + d0, vj);
#pragma unroll
      for (int cc = 0; cc < 3; ++cc){
        const int c = (cc == 0) ? 2 : (cc - 1);
        s8v ah, al;
        if (c == 2){
          float vp[8];
#pragma unroll
          for (int t = 0; t < 8; ++t) vp[t] = vi[t] * vj[t];
          cvt8(vp, ah, al);
        } else if (c == 0) cvt8(vi, ah, al);
        else               cvt8(vj, ah, al);
        const int ks = c * 4 + d4;
#pragma unroll
        for (int nt = 0; nt < 4; ++nt){
          const int fo = ((nt * 12 + ks) * 64 + lane) << 3;
          const s8v bh = *(const s8v*)(pk + S1H + fo);
          const s8v bl = *(const s8v*)(pk + S1L + fo);
          acc[nt] = MFMA16(ah, bh, acc[nt], 0, 0, 0);
          acc[nt] = MFMA16(al, bh, acc[nt], 0, 0, 0);
          acc[nt] = MFMA16(ah, bl, acc[nt], 0, 0, 0);
        }
      }
    }
#pragma unroll
    for (int nt = 0; nt < 4; ++nt){
      const float bias = sb1[nt * 16 + m];
#pragma unroll
      for (int reg = 0; reg < 4; ++reg){
        const float v = gelu_f(acc[nt][reg] + bias);
        const int idx = (quad * 4 + reg) * 64 + ((nt * 16 + m) ^ (quad << 4));
        const unsigned uv = __float_as_uint(v);
        hh[wave][idx] = (short)(uv >> 16);
        const float lo = v - __uint_as_float(uv & 0xFFFF0000u);
        hh[wave][1024 + idx] = (short)(__float_as_uint(lo) >> 16);
      }
    }
    s8v a2h[2], a2l[2];
#pragma unroll
    for (int k2 = 0; k2 < 2; ++k2){
      const int off = m * 64 + ((k2 * 32 + quad * 8) ^ ((m >> 2) << 4));
      a2h[k2] = *(const s8v*)&hh[wave][off];
      a2l[k2] = *(const s8v*)&hh[wave][1024 + off];
    }
    f4v acc2[4];
#pragma unroll
    for (int nt = 0; nt < 4; ++nt) acc2[nt] = (f4v){0.f,0.f,0.f,0.f};
#pragma unroll
    for (int k2 = 0; k2 < 2; ++k2)
#pragma unroll
      for (int nt = 0; nt < 4; ++nt){
        const int fo = ((nt * 2 + k2) * 64 + lane) << 3;
        const s8v bh = *(const s8v*)(pk + S2H + fo);
        const s8v bl = *(const s8v*)(pk + S2L + fo);
        acc2[nt] = MFMA16(a2h[k2], bh, acc2[nt], 0, 0, 0);
        acc2[nt] = MFMA16(a2l[k2], bh, acc2[nt], 0, 0, 0);
        acc2[nt] = MFMA16(a2h[k2], bl, acc2[nt], 0, 0, 0);
      }
#pragma unroll
    for (int nt = 0; nt < 4; ++nt){
      const float bias = sb2[nt * 16 + m];
#pragma unroll
      for (int reg = 0; reg < 4; ++reg){
        const float v = gelu_f(acc2[nt][reg] + bias);
        const int idx = (quad * 4 + reg) * 64 + ((nt * 16 + m) ^ (quad << 4));
        const unsigned uv = __float_as_uint(v);
        hh[wave][idx] = (short)(uv >> 16);
        const float lo = v - __uint_as_float(uv & 0xFFFF0000u);
        hh[wave][1024 + idx] = (short)(__float_as_uint(lo) >> 16);
      }
    }
    s8v a3h[2], a3l[2];
#pragma unroll
    for (int k3 = 0; k3 < 2; ++k3){
      const int off = m * 64 + ((k3 * 32 + quad * 8) ^ ((m >> 2) << 4));
      a3h[k3] = *(const s8v*)&hh[wave][off];
      a3l[k3] = *(const s8v*)&hh[wave][1024 + off];
    }
    f4v acc3 = (f4v){0.f,0.f,0.f,0.f};
#pragma unroll
    for (int k3 = 0; k3 < 2; ++k3){
      const int fo = (k3 * 64 + lane) << 3;
      const s8v bh = *(const s8v*)(pk + S3H + fo);
      const s8v bl = *(const s8v*)(pk + S3L + fo);
      acc3 = MFMA16(a3h[k3], bh, acc3, 0, 0, 0);
      acc3 = MFMA16(a3l[k3], bh, acc3, 0, 0, 0);
      acc3 = MFMA16(a3h[k3], bl, acc3, 0, 0, 0);
    }
    const float bias3 = sb3[m];
#pragma unroll
    for (int reg = 0; reg < 4; ++reg){
      const int R = rowBase + quad * 4 + reg;
      if (R < 1022) outK[R * 16 + m] = acc3[reg] + bias3;
    }
    return;
  }

  // --------------------------- pair path (pure bf16) -----------------------
  const int rowBase = blockIdx.x * 128 + wave * 32;
  int oi[2], oj[2];
  int qa2[2][2], qb2[2][2];
  float invLr[2][2];
#pragma unroll
  for (int s = 0; s < 2; ++s){
    {
      const int r = rowBase + s * 16 + m;
      const int p = r >> 1, b = r & 1;
      const int i = inv_tri(p), j = p - i * (i + 1) / 2;
      oi[s] = (i * 2 + b) * 128;
      oj[s] = (j * 2 + b) * 128;
    }
    {
      const int p0 = (rowBase + s * 16 + quad * 4) >> 1;
      const int i0 = inv_tri(p0), j0 = p0 - i0 * (i0 + 1) / 2;
      qa2[s][0] = (i0 + 1) * 128; qb2[s][0] = j0 * 128;
      invLr[s][0] = 1.0f / (float)(i0 - j0 + 1);
      int i1 = i0, j1 = j0 + 1;
      if (j1 > i1){ i1 = i0 + 1; j1 = 0; }
      qa2[s][1] = (i1 + 1) * 128; qb2[s][1] = j1 * 128;
      invLr[s][1] = 1.0f / (float)(i1 - j1 + 1);
    }
  }

  f4v acc[2][4];
#pragma unroll
  for (int s = 0; s < 2; ++s)
#pragma unroll
    for (int nt = 0; nt < 4; ++nt) acc[s][nt] = (f4v){0.f,0.f,0.f,0.f};

  // layer-1 Hadamard GEMM, K=128, bf16-RTN single MFMA
  for (int d4 = 0; d4 < 4; ++d4){
    const int d0 = d4 * 32 + quad * 8;
    s8v ah[2];
#pragma unroll
    for (int s = 0; s < 2; ++s){
      float vi[8], vj[8];
      ld8(x + oi[s] + d0, vi); ld8(x + oj[s] + d0, vj);
#pragma unroll
      for (int t = 0; t < 8; ++t) vi[t] *= vj[t];
      cvt8r(vi, ah[s]);
    }
#pragma unroll
    for (int nt = 0; nt < 4; ++nt){
      const int fo = ((nt * 24 + 8 + d4) * 64 + lane) << 3;
      const s8v bh = *(const s8v*)(pk + W1H + fo);
#pragma unroll
      for (int s = 0; s < 2; ++s)
        acc[s][nt] = MFMA16(ah[s], bh, acc[s][nt], 0, 0, 0);
    }
  }
  // epilogue 1: + Ya[i] + Yb[j] + invL*(Q[i+1]-Q[j]) + b1, gelu -> LDS (RTN)
#pragma unroll
  for (int s = 0; s < 2; ++s)
#pragma unroll
    for (int nt = 0; nt < 4; ++nt){
      const int col = nt * 16 + m;
      const float bias = b1[col];
#pragma unroll
      for (int reg = 0; reg < 4; ++reg){
        const int k = reg >> 1, bb = reg & 1;
        const int off = bb * 64 + col;
        const float add = Ya[qa2[s][k] - 128 + off] + Yb[qb2[s][k] + off]
                        + invLr[s][k] * (Q[qa2[s][k] + off] - Q[qb2[s][k] + off]);
        const float v = gelu_f(acc[s][nt][reg] + bias + add);
        const int idx = (s * 16 + quad * 4 + reg) * 64 + ((nt * 16 + m) ^ (quad << 4));
        hh[wave][idx] = (short)f2bf(v);
      }
    }
  s8v a2h[2][2];
#pragma unroll
  for (int s = 0; s < 2; ++s)
#pragma unroll
    for (int k2 = 0; k2 < 2; ++k2){
      const int off = (s * 16 + m) * 64 + ((k2 * 32 + quad * 8) ^ ((m >> 2) << 4));
      a2h[s][k2] = *(const s8v*)&hh[wave][off];
    }
  // layer 2 (bf16)
  f4v acc2[2][4];
#pragma unroll
  for (int s = 0; s < 2; ++s)
#pragma unroll
    for (int nt = 0; nt < 4; ++nt) acc2[s][nt] = (f4v){0.f,0.f,0.f,0.f};
#pragma unroll
  for (int k2 = 0; k2 < 2; ++k2)
#pragma unroll
    for (int nt = 0; nt < 4; ++nt){
      const int fo = ((nt * 2 + k2) * 64 + lane) << 3;
      const s8v bh = *(const s8v*)(pk + W2H + fo);
#pragma unroll
      for (int s = 0; s < 2; ++s)
        acc2[s][nt] = MFMA16(a2h[s][k2], bh, acc2[s][nt], 0, 0, 0);
    }
#pragma unroll
  for (int s = 0; s < 2; ++s)
#pragma unroll
    for (int nt = 0; nt < 4; ++nt){
      const float bias = b2[nt * 16 + m];
#pragma unroll
      for (int reg = 0; reg < 4; ++reg){
        const float v = gelu_f(acc2[s][nt][reg] + bias);
        const int idx = (s * 16 + quad * 4 + reg) * 64 + ((nt * 16 + m) ^ (quad << 4));
        hh[wave][idx] = (short)f2bf(v);
      }
    }
  s8v a3h[2][2];
#pragma unroll
  for (int s = 0; s < 2; ++s)
#pragma unroll
    for (int k3 = 0; k3 < 2; ++k3){
      const int off = (s * 16 + m) * 64 + ((k3 * 32 + quad * 8) ^ ((m >> 2) << 4));
      a3h[s][k3] = *(const s8v*)&hh[wave][off];
    }
  // layer 3 (bf16)
  f4v acc3[2];
  acc3[0] = (f4v){0.f,0.f,0.f,0.f};
  acc3[1] = (f4v){0.f,0.f,0.f,0.f};
#pragma unroll
  for (int k3 = 0; k3 < 2; ++k3){
    const int fo = (k3 * 64 + lane) << 3;
    const s8v bh = *(const s8v*)(pk + W3H + fo);
#pragma unroll
    for (int s = 0; s < 2; ++s)
      acc3[s] = MFMA16(a3h[s][k3], bh, acc3[s], 0, 0, 0);
  }
  const float bias3 = b3[m];
#pragma unroll
  for (int s = 0; s < 2; ++s)
#pragma unroll
    for (int reg = 0; reg < 4; ++reg){
      const int k = reg >> 1, bb = reg & 1;
      const int i = (qa2[s][k] >> 7) - 1, j = qb2[s][k] >> 7;
      Sd[((i * 512 + j) * 2 + bb) * 16 + m] = acc3[s][reg] + bias3;
    }
}

// ------------- MFMA fused conv1(pad2)+gelu+conv2+len-scale -----------------
// pure bf16-RTN; sT 400x24, hT 324x24 shorts -> 34.8KB LDS, 4 blocks/CU.
// r13: constant fast path for X0 >= Y0+32 (receptive field entirely above
// the diagonal -> S=0 -> out = lenBA * Kc[oc]); 45% of blocks skip all work.
__global__ __launch_bounds__(256) void conv_mfma(
    const float* __restrict__ Sd, const short* __restrict__ pk,
    const float* __restrict__ cb1, const float* __restrict__ cb2,
    const float* __restrict__ Kc, float* __restrict__ out)
{
  __shared__ __attribute__((aligned(16))) short sT[9600];   // 400 px * 24
  __shared__ __attribute__((aligned(16))) short hT[7776];   // 324 px * 24

  const int tid = threadIdx.x;
  const int X0 = blockIdx.x * 16, Y0 = blockIdx.y * 16, bb = blockIdx.z;
  const int lane = tid & 63, wave = tid >> 6;
  const int mcol = lane & 15, quad = lane >> 4;

  if (X0 >= Y0 + 32){
    // constant region: every receptive pixel has gx > gy -> S = 0
    const float K = Kc[mcol];
#pragma unroll
    for (int t2 = 0; t2 < 4; ++t2)
#pragma unroll
      for (int reg = 0; reg < 4; ++reg){
        const int p = (wave * 4 + t2) * 16 + quad * 4 + reg;
        const int Y = Y0 + (p >> 4), X = X0 + (p & 15);
        int l = X - Y;                 // X > Y here
        out[((Y * 512 + X) * 2 + bb) * 16 + mcol] = K * (float)l;
      }
    return;
  }

  const int tq = quad >> 1, icl0 = (quad & 1) * 8;

  for (int e = tid; e < 1600; e += 256){
    const int q = e & 3, p = e >> 2;
    const int row = p / 20, col = p % 20;
    const int gy = Y0 - 2 + row, gx = X0 - 2 + col;
    float4 v = make_float4(0.f, 0.f, 0.f, 0.f);
    if (gy >= 0 && gy < 512 && gx >= 0 && gx <= gy)
      v = *(const float4*)(Sd + (((gy * 512 + gx) * 2 + bb) * 16 + q * 4));
    int2 pkd;
    pkd.x = ((unsigned)f2bf(v.y) << 16) | (unsigned)f2bf(v.x);
    pkd.y = ((unsigned)f2bf(v.w) << 16) | (unsigned)f2bf(v.z);
    *(int2*)&sT[p * 24 + q * 4] = pkd;
  }
  __syncthreads();

  int base1[6];
#pragma unroll
  for (int it = 0; it < 6; ++it){
    int p = (wave * 6 + it) * 16 + mcol; if (p > 323) p = 323;
    const int u = p / 18, v = p - u * 18;
    base1[it] = (u * 20 + v) * 24 + icl0;
  }
  int base2[4];
#pragma unroll
  for (int t2 = 0; t2 < 4; ++t2){
    const int p = (wave * 4 + t2) * 16 + mcol;
    base2[t2] = (p >> 4) * 18 + (p & 15);
  }

  const float bias2 = cb2[mcol];
  f4v acc2[4];
#pragma unroll
  for (int t2 = 0; t2 < 4; ++t2) acc2[t2] = (f4v){0.f,0.f,0.f,0.f};

  for (int chunk = 0; chunk < 3; ++chunk){
    f4v c1[6];
#pragma unroll
    for (int it = 0; it < 6; ++it) c1[it] = (f4v){0.f,0.f,0.f,0.f};
    for (int ks = 0; ks < 5; ++ks){
      int tap = ks * 2 + tq; if (tap > 8) tap = 8;   // tap9 -> B is zero
      const int ky = tap / 3, kx = tap - ky * 3;
      const int off1 = (ky * 20 + kx) * 24;
      const int fo = ((chunk * 5 + ks) * 64 + lane) << 3;
      const s8v b1h = *(const s8v*)(pk + C1H + fo);
#pragma unroll
      for (int it = 0; it < 6; ++it){
        const s8v ah = *(const s8v*)&sT[base1[it] + off1];
        c1[it] = MFMA16(ah, b1h, c1[it], 0, 0, 0);
      }
    }
    const float bias1 = cb1[chunk * 16 + mcol];
#pragma unroll
    for (int it = 0; it < 6; ++it){
      const int pb = (wave * 6 + it) * 16 + quad * 4;
#pragma unroll
      for (int reg = 0; reg < 4; ++reg){
        const int p = pb + reg;
        if (p < 324)
          hT[p * 24 + mcol] = (short)f2bf(gelu_f(c1[it][reg] + bias1));
      }
    }
    __syncthreads();
    for (int ks = 0; ks < 5; ++ks){
      int tap = ks * 2 + tq; if (tap > 8) tap = 8;
      const int ky = tap / 3, kx = tap - ky * 3;
      const int off2 = ky * 18 + kx;
      const int fo = ((chunk * 5 + ks) * 64 + lane) << 3;
      const s8v b2h = *(const s8v*)(pk + C2H + fo);
#pragma unroll
      for (int t2 = 0; t2 < 4; ++t2){
        const s8v ah = *(const s8v*)&hT[(base2[t2] + off2) * 24 + icl0];
        acc2[t2] = MFMA16(ah, b2h, acc2[t2], 0, 0, 0);
      }
    }
    __syncthreads();
  }
#pragma unroll
  for (int t2 = 0; t2 < 4; ++t2){
#pragma unroll
    for (int reg = 0; reg < 4; ++reg){
      const int p = (wave * 4 + t2) * 16 + quad * 4 + reg;
      const int Y = Y0 + (p >> 4), X = X0 + (p & 15);
      int l = Y - X; if (l < 0) l = -l; if (l < 1) l = 1;
      out[((Y * 512 + X) * 2 + bb) * 16 + mcol] = (acc2[t2][reg] + bias2) * (float)l;
    }
  }
}

// ---------------------------------------------------------------------------
extern "C" void kernel_launch(void* const* d_in, const int* in_sizes, int n_in,
                              void* d_out, int out_size, void* d_ws, size_t ws_size,
                              hipStream_t stream)
{
  (void)in_sizes; (void)n_in; (void)out_size; (void)ws_size;
  const float* x   = (const float*)d_in[0];
  const float* w1  = (const float*)d_in[1];
  const float* b1  = (const float*)d_in[2];
  const float* w2  = (const float*)d_in[3];
  const float* b2  = (const float*)d_in[4];
  const float* w3  = (const float*)d_in[5];
  const float* b3  = (const float*)d_in[6];
  const float* sw1 = (const float*)d_in[7];
  const float* sb1 = (const float*)d_in[8];
  const float* sw2 = (const float*)d_in[9];
  const float* sb2 = (const float*)d_in[10];
  const float* sw3 = (const float*)d_in[11];
  const float* sb3 = (const float*)d_in[12];
  const float* cw1 = (const float*)d_in[13];
  const float* cb1 = (const float*)d_in[14];
  const float* cw2 = (const float*)d_in[15];
  const float* cb2 = (const float*)d_in[16];

  float* ws  = (float*)d_ws;
  float* xc  = ws;
  float* x2c = ws + 131328;
  float* x3c = ws + 262656;
  float* Sd  = ws + 393984;
  short* pk  = (short*)(ws + 8782592);
  float* Ya  = ws + 8881920;
  float* Yb  = ws + 8947456;
  float* Q   = ws + 9012992;
  float* segTot = ws + 9078656;
  float* Kc  = ws + 9103232;
  float* outS = (float*)d_out;
  float* outK = outS + 8388608;

  setup_fused<<<485, 256, 0, stream>>>(x, w1, w2, w3, sw1, sw2, sw3, cw1, cw2,
                                       cb1, cb2, xc, x2c, x3c, pk, segTot, Kc);
  scan_fix<<<96, 256, 0, stream>>>(xc, x2c, x3c, segTot);
  pre_gemm<<<33, 256, 0, stream>>>(x, xc, x2c, x3c, pk, Ya, Yb, Q);
  pair_mlp<<<2068, 256, 0, stream>>>(x, pk, Ya, Yb, Q, b1, b2, b3,
                                     sb1, sb2, sb3, Sd, outK);
  conv_mfma<<<dim3(32, 32, 2), 256, 0, stream>>>(Sd, pk, cb1, cb2, Kc, outS);
}